// Round 6
// baseline (1505.920 us; speedup 1.0000x reference)
//
#include <hip/hip_runtime.h>

#define IN_CH 128
#define HID   256
#define PB_VT 16            // edges per thread in partition pass (4096/block)

typedef __attribute__((ext_vector_type(8))) short bf16x8;
typedef __attribute__((ext_vector_type(4))) float f32x4;
typedef __attribute__((ext_vector_type(8))) unsigned short ushort8;

__device__ __forceinline__ ushort f2b(float f) {
    unsigned u = __float_as_uint(f);
    unsigned r = (u + 0x7fffu + ((u >> 16) & 1u)) >> 16;
    return (ushort)r;
}
__device__ __forceinline__ float b2f(ushort h) {
    return __uint_as_float(((unsigned)h) << 16);
}

// ================= sort infrastructure =================
// fine counts: count[0..N) = graph by dst, count[N..2N) = candidates by a
// coarse counts: cntG/cntP per 256-node bucket
__global__ void hist2c_kernel(const int* __restrict__ dst, const int* __restrict__ edges,
                              int* __restrict__ count, int* __restrict__ cntG,
                              int* __restrict__ cntP, int N, int E, int E2) {
    int e = blockIdx.x * 256 + threadIdx.x;
    if (e < E)  { int d = dst[e];                 atomicAdd(&count[d], 1);     atomicAdd(&cntG[d >> 8], 1); }
    if (e < E2) { int a = edges[(size_t)e * 2];   atomicAdd(&count[N + a], 1); atomicAdd(&cntP[a >> 8], 1); }
}

__global__ void scan1_kernel(const int* __restrict__ count, int* __restrict__ offs,
                             int* __restrict__ bsums, int M) {
    __shared__ int s[256];
    int t = threadIdx.x;
    int i = blockIdx.x * 256 + t;
    int v = (i < M) ? count[i] : 0;
    s[t] = v;
    __syncthreads();
    for (int d = 1; d < 256; d <<= 1) {
        int u = (t >= d) ? s[t - d] : 0;
        __syncthreads();
        s[t] += u;
        __syncthreads();
    }
    if (i < M) offs[i] = s[t] - v;
    if (t == 255) bsums[blockIdx.x] = s[255];
}

__global__ void scan2_kernel(int* __restrict__ bsums, int NB) {   // NB <= 1024
    __shared__ int s[1024];
    int t = threadIdx.x;
    int v = (t < NB) ? bsums[t] : 0;
    s[t] = v;
    __syncthreads();
    for (int d = 1; d < 1024; d <<= 1) {
        int u = (t >= d) ? s[t - d] : 0;
        __syncthreads();
        s[t] += u;
        __syncthreads();
    }
    if (t < NB) bsums[t] = s[t] - v;
}

__global__ void scan3_kernel(int* __restrict__ offs, const int* __restrict__ bsums,
                             int* __restrict__ cursor, int M) {
    int i = blockIdx.x * 256 + threadIdx.x;
    if (i < M) {
        int o = offs[i] + bsums[i >> 8];
        offs[i] = o;
        cursor[i] = o;
    }
}

// single-block exclusive scans of the coarse bucket counts (NBUK <= 512)
__global__ void coarse_scan_kernel(const int* __restrict__ cntG, const int* __restrict__ cntP,
                                   int* __restrict__ bstartG, int* __restrict__ bcursorG,
                                   int* __restrict__ bstartP, int* __restrict__ bcursorP,
                                   int NBUK) {
    __shared__ int s[512];
    int t = threadIdx.x;
    int v = (t < NBUK) ? cntG[t] : 0;
    s[t] = v;
    __syncthreads();
    for (int d = 1; d < 512; d <<= 1) {
        int u = (t >= d) ? s[t - d] : 0;
        __syncthreads(); s[t] += u; __syncthreads();
    }
    if (t < NBUK) { int o = s[t] - v; bstartG[t] = o; bcursorG[t] = o; }
    __syncthreads();
    v = (t < NBUK) ? cntP[t] : 0;
    s[t] = v;
    __syncthreads();
    for (int d = 1; d < 512; d <<= 1) {
        int u = (t >= d) ? s[t - d] : 0;
        __syncthreads(); s[t] += u; __syncthreads();
    }
    if (t < NBUK) { int o = s[t] - v; bstartP[t] = o; bcursorP[t] = o; }
}

// partition graph edges into coarse buckets (block multi-split, amp~1 writes)
__global__ __launch_bounds__(256)
void partition_g_kernel(const int* __restrict__ src, const int* __restrict__ dst,
                        int* __restrict__ bcursor, int* __restrict__ tmpD,
                        int* __restrict__ tmpS, int E) {
    __shared__ int hist[512], base[512], rnk[512];
    int t = threadIdx.x;
    long long e0 = (long long)blockIdx.x * (256 * PB_VT);
    for (int i = t; i < 512; i += 256) { hist[i] = 0; rnk[i] = 0; }
    __syncthreads();
    int key[PB_VT], pay[PB_VT];
#pragma unroll
    for (int i = 0; i < PB_VT; i++) {
        long long e = e0 + i * 256 + t;
        if (e < E) {
            key[i] = dst[e]; pay[i] = src[e];
            atomicAdd(&hist[key[i] >> 8], 1);
        } else key[i] = -1;
    }
    __syncthreads();
    for (int i = t; i < 512; i += 256) {
        int c = hist[i];
        base[i] = (c > 0) ? atomicAdd(&bcursor[i], c) : 0;
    }
    __syncthreads();
#pragma unroll
    for (int i = 0; i < PB_VT; i++) {
        if (key[i] >= 0) {
            int b = key[i] >> 8;
            int pos = base[b] + atomicAdd(&rnk[b], 1);
            tmpD[pos] = key[i];
            tmpS[pos] = pay[i];
        }
    }
}

// partition candidate pairs by a-node; payload (b,e)
__global__ __launch_bounds__(256)
void partition_p_kernel(const int* __restrict__ edges, int* __restrict__ bcursor,
                        int* __restrict__ tmpA, unsigned long long* __restrict__ tmpBE,
                        int E2) {
    __shared__ int hist[512], base[512], rnk[512];
    int t = threadIdx.x;
    long long e0 = (long long)blockIdx.x * (256 * PB_VT);
    for (int i = t; i < 512; i += 256) { hist[i] = 0; rnk[i] = 0; }
    __syncthreads();
    int ka[PB_VT], kb[PB_VT];
#pragma unroll
    for (int i = 0; i < PB_VT; i++) {
        long long e = e0 + i * 256 + t;
        if (e < E2) {
            int2 ab = *(const int2*)(edges + (size_t)e * 2);
            ka[i] = ab.x; kb[i] = ab.y;
            atomicAdd(&hist[ka[i] >> 8], 1);
        } else ka[i] = -1;
    }
    __syncthreads();
    for (int i = t; i < 512; i += 256) {
        int c = hist[i];
        base[i] = (c > 0) ? atomicAdd(&bcursor[i], c) : 0;
    }
    __syncthreads();
#pragma unroll
    for (int i = 0; i < PB_VT; i++) {
        if (ka[i] >= 0) {
            int b = ka[i] >> 8;
            long long e = e0 + i * 256 + t;
            int pos = base[b] + atomicAdd(&rnk[b], 1);
            tmpA[pos] = ka[i];
            tmpBE[pos] = ((unsigned long long)(unsigned)kb[i] << 32) | (unsigned)e;
        }
    }
}

// fine scatter within each bucket (output windows 16-32 KB -> L2-resident)
__global__ __launch_bounds__(256)
void fine_scatter_kernel(const int* __restrict__ tmpD, const int* __restrict__ tmpS,
                         const int* __restrict__ tmpA, const unsigned long long* __restrict__ tmpBE,
                         const int* __restrict__ bstartG, const int* __restrict__ cntG,
                         const int* __restrict__ bstartP, const int* __restrict__ cntP,
                         int* __restrict__ cursor, int* __restrict__ nbr,
                         unsigned long long* __restrict__ pairs,
                         int N, int E, int NBUK) {
    int blk = blockIdx.x, t = threadIdx.x;
    if (blk < NBUK) {
        int s = bstartG[blk], c = cntG[blk];
        for (int i = t; i < c; i += 256) {
            int d = tmpD[s + i], v = tmpS[s + i];
            int pos = atomicAdd(&cursor[d], 1);
            nbr[pos] = v;
        }
    } else {
        blk -= NBUK;
        int s = bstartP[blk], c = cntP[blk];
        for (int i = t; i < c; i += 256) {
            int a = tmpA[s + i];
            unsigned long long be = tmpBE[s + i];
            int pos = atomicAdd(&cursor[N + a], 1) - E;
            pairs[pos] = be;
        }
    }
}

// ================= bf16 conversions =================
__global__ void cvt_kernel(const float* __restrict__ in, ushort* __restrict__ o, int n4) {
    int i = blockIdx.x * 256 + threadIdx.x;
    if (i < n4) {
        float4 v = ((const float4*)in)[i];
        ushort4 u;
        u.x = f2b(v.x); u.y = f2b(v.y); u.z = f2b(v.z); u.w = f2b(v.w);
        ((ushort4*)o)[i] = u;
    }
}

// Wt[n][k] bf16 (n-major, k contiguous). PERM_K: A stored with
// P(c)=(c&~63)|((c&15)*4+((c>>4)&3)); stored k uses logical c=Pinv.
template<bool PERM_K>
__global__ void prep_w_kernel(const float* __restrict__ Wl, const float* __restrict__ Wr,
                              ushort* __restrict__ Wt, int KH) {
    int ktot = 2 * KH;
    int idx = blockIdx.x * 256 + threadIdx.x;
    if (idx >= 256 * ktot) return;
    int n = idx / ktot, k = idx % ktot;
    int kh = (k < KH) ? k : (k - KH);
    int c = kh;
    if (PERM_K) {
        int j = kh & 63;
        c = (kh & ~63) | ((j & 3) * 16 + (j >> 2));
    }
    float v = (k < KH) ? Wl[(size_t)c * 256 + n] : Wr[(size_t)c * 256 + n];
    Wt[idx] = f2b(v);
}

// ================= gather-mean aggregation =================
__global__ void agg1_kernel(const ushort* __restrict__ xb, const int* __restrict__ nbr,
                            const int* __restrict__ offs, const int* __restrict__ count,
                            ushort* __restrict__ agg, int N) {
    int w = blockIdx.x * 4 + (threadIdx.x >> 6);
    if (w >= N) return;
    int lane = threadIdx.x & 63;
    int grp = lane >> 4, gl = lane & 15;
    int start = offs[w], cnt = count[w];
    float acc[8];
#pragma unroll
    for (int i = 0; i < 8; i++) acc[i] = 0.0f;
    for (int j = grp; j < cnt; j += 4) {
        int s = nbr[start + j];
        ushort8 v = *(const ushort8*)(xb + (size_t)s * IN_CH + gl * 8);
#pragma unroll
        for (int i = 0; i < 8; i++) acc[i] += b2f(v[i]);
    }
#pragma unroll
    for (int i = 0; i < 8; i++) acc[i] += __shfl_xor(acc[i], 16, 64);
#pragma unroll
    for (int i = 0; i < 8; i++) acc[i] += __shfl_xor(acc[i], 32, 64);
    if (grp == 0) {
        float r = 1.0f / fmaxf((float)cnt, 1.0f);
        ushort8 o;
#pragma unroll
        for (int i = 0; i < 8; i++) o[i] = f2b(acc[i] * r);
        *(ushort8*)(agg + (size_t)w * IN_CH + gl * 8) = o;
    }
}

__global__ void agg2_kernel(const ushort* __restrict__ h, const int* __restrict__ nbr,
                            const int* __restrict__ offs, const int* __restrict__ count,
                            ushort* __restrict__ agg, int N) {
    int w = blockIdx.x * 4 + (threadIdx.x >> 6);
    if (w >= N) return;
    int lane = threadIdx.x & 63;
    int half = lane >> 5, hl = lane & 31;
    int start = offs[w], cnt = count[w];
    float a0[8], a1[8];
#pragma unroll
    for (int i = 0; i < 8; i++) { a0[i] = 0.0f; a1[i] = 0.0f; }
    int j = half;
    for (; j + 2 < cnt; j += 4) {
        int s0 = nbr[start + j];
        int s1 = nbr[start + j + 2];
        ushort8 v0 = *(const ushort8*)(h + (size_t)s0 * HID + hl * 8);
        ushort8 v1 = *(const ushort8*)(h + (size_t)s1 * HID + hl * 8);
#pragma unroll
        for (int i = 0; i < 8; i++) { a0[i] += b2f(v0[i]); a1[i] += b2f(v1[i]); }
    }
    if (j < cnt) {
        int s0 = nbr[start + j];
        ushort8 v0 = *(const ushort8*)(h + (size_t)s0 * HID + hl * 8);
#pragma unroll
        for (int i = 0; i < 8; i++) a0[i] += b2f(v0[i]);
    }
#pragma unroll
    for (int i = 0; i < 8; i++) {
        a0[i] += a1[i];
        a0[i] += __shfl_xor(a0[i], 32, 64);
    }
    if (half == 0) {
        float r = 1.0f / fmaxf((float)cnt, 1.0f);
        ushort8 o;
#pragma unroll
        for (int i = 0; i < 8; i++) o[i] = f2b(a0[i] * r);
        *(ushort8*)(agg + (size_t)w * HID + hl * 8) = o;
    }
}

// ================= MFMA GEMM, permuted coalesced epilogue =================
template<int KTOT, bool RELU>
__global__ __launch_bounds__(256, 2)
void sage_gemm_mfma(const ushort* __restrict__ Aleft, const ushort* __restrict__ Aright,
                    const ushort* __restrict__ Wt, const float* __restrict__ bias,
                    ushort* __restrict__ out, int N) {
    constexpr int KH = KTOT / 2;
    constexpr int LDA = 40;
    __shared__ ushort As[64][LDA];
    __shared__ ushort Bs[256][LDA];

    const int t = threadIdx.x;
    const int wave = t >> 6;
    const int lane = t & 63;
    const int quad = lane >> 4;
    const int l16  = lane & 15;
    const int rowBase = blockIdx.x * 64;

    const int sRow = t >> 2;
    const int sChk = (t & 3) << 3;
    const bool aRowOK = (rowBase + sRow) < N;

    f32x4 acc[4][4];
#pragma unroll
    for (int i = 0; i < 4; i++)
#pragma unroll
        for (int j = 0; j < 4; j++) acc[i][j] = (f32x4)0.0f;

    for (int k0 = 0; k0 < KTOT; k0 += 32) {
        ulonglong2 a16 = {0ull, 0ull};
        if (aRowOK) {
            const ushort* Ap = (k0 < KH)
                ? (Aleft  + (size_t)(rowBase + sRow) * KH + (k0 + sChk))
                : (Aright + (size_t)(rowBase + sRow) * KH + (k0 - KH + sChk));
            a16 = *(const ulonglong2*)Ap;
        }
        ulonglong2 b16[4];
#pragma unroll
        for (int i = 0; i < 4; i++) {
            int n = sRow + i * 64;
            b16[i] = *(const ulonglong2*)(Wt + (size_t)n * KTOT + k0 + sChk);
        }

        __syncthreads();
        *(ulonglong2*)&As[sRow][sChk] = a16;
#pragma unroll
        for (int i = 0; i < 4; i++)
            *(ulonglong2*)&Bs[sRow + i * 64][sChk] = b16[i];
        __syncthreads();

        bf16x8 af[4], bf[4];
#pragma unroll
        for (int mt = 0; mt < 4; mt++)
            af[mt] = *(const bf16x8*)&As[mt * 16 + l16][quad * 8];
#pragma unroll
        for (int nt = 0; nt < 4; nt++)
            bf[nt] = *(const bf16x8*)&Bs[wave * 64 + nt * 16 + l16][quad * 8];
#pragma unroll
        for (int mt = 0; mt < 4; mt++)
#pragma unroll
            for (int nt = 0; nt < 4; nt++)
                acc[mt][nt] = __builtin_amdgcn_mfma_f32_16x16x32_bf16(
                    af[mt], bf[nt], acc[mt][nt], 0, 0, 0);
    }

    float bv[4];
#pragma unroll
    for (int nt = 0; nt < 4; nt++) bv[nt] = bias[wave * 64 + nt * 16 + l16];
#pragma unroll
    for (int mt = 0; mt < 4; mt++) {
#pragma unroll
        for (int reg = 0; reg < 4; reg++) {
            int row = rowBase + mt * 16 + quad * 4 + reg;
            if (row < N) {
                ushort4 o;
                {
                    float v0 = acc[mt][0][reg] + bv[0];
                    float v1 = acc[mt][1][reg] + bv[1];
                    float v2 = acc[mt][2][reg] + bv[2];
                    float v3 = acc[mt][3][reg] + bv[3];
                    if (RELU) {
                        v0 = fmaxf(v0, 0.0f); v1 = fmaxf(v1, 0.0f);
                        v2 = fmaxf(v2, 0.0f); v3 = fmaxf(v3, 0.0f);
                    }
                    o.x = f2b(v0); o.y = f2b(v1); o.z = f2b(v2); o.w = f2b(v3);
                }
                *(ushort4*)(out + (size_t)row * 256 + wave * 64 + l16 * 4) = o;
            }
        }
    }
}

// ================= decode: one wave per a-node over a-sorted pairs =================
__global__ void decode2_kernel(const ushort* __restrict__ z,
                               const unsigned long long* __restrict__ pairs,
                               const int* __restrict__ offsA, const int* __restrict__ countA,
                               float* __restrict__ out, int N, int baseE) {
    int a = blockIdx.x * 4 + (threadIdx.x >> 6);
    if (a >= N) return;
    int cnt = countA[a];
    if (cnt == 0) return;
    int lane = threadIdx.x & 63;
    int half = lane >> 5, hl = lane & 31;
    int start = offsA[a] - baseE;

    float ar[8];
    {
        ushort8 va = *(const ushort8*)(z + (size_t)a * HID + hl * 8);
#pragma unroll
        for (int i = 0; i < 8; i++) ar[i] = b2f(va[i]);
    }

    int j = half;
    for (; j + 2 < cnt; j += 4) {
        unsigned long long p0 = pairs[start + j];
        unsigned long long p1 = pairs[start + j + 2];
        int b0 = (int)(p0 >> 32), e0 = (int)(p0 & 0xffffffffu);
        int b1 = (int)(p1 >> 32), e1 = (int)(p1 & 0xffffffffu);
        ushort8 v0 = *(const ushort8*)(z + (size_t)b0 * HID + hl * 8);
        ushort8 v1 = *(const ushort8*)(z + (size_t)b1 * HID + hl * 8);
        float s0 = 0.f, s1 = 0.f;
#pragma unroll
        for (int i = 0; i < 8; i++) { s0 = fmaf(ar[i], b2f(v0[i]), s0);
                                      s1 = fmaf(ar[i], b2f(v1[i]), s1); }
#pragma unroll
        for (int off = 1; off < 32; off <<= 1) { s0 += __shfl_xor(s0, off, 64);
                                                 s1 += __shfl_xor(s1, off, 64); }
        if (hl == 0) { out[e0] = s0; out[e1] = s1; }
    }
    if (j < cnt) {
        unsigned long long p0 = pairs[start + j];
        int b0 = (int)(p0 >> 32), e0 = (int)(p0 & 0xffffffffu);
        ushort8 v0 = *(const ushort8*)(z + (size_t)b0 * HID + hl * 8);
        float s0 = 0.f;
#pragma unroll
        for (int i = 0; i < 8; i++) s0 = fmaf(ar[i], b2f(v0[i]), s0);
#pragma unroll
        for (int off = 1; off < 32; off <<= 1) s0 += __shfl_xor(s0, off, 64);
        if (hl == 0) out[e0] = s0;
    }
}

extern "C" void kernel_launch(void* const* d_in, const int* in_sizes, int n_in,
                              void* d_out, int out_size, void* d_ws, size_t ws_size,
                              hipStream_t stream) {
    const float* x    = (const float*)d_in[0];
    const int* eidx   = (const int*)d_in[1];
    const int* edges  = (const int*)d_in[2];
    const float* W1l  = (const float*)d_in[3];
    const float* b1   = (const float*)d_in[4];
    const float* W1r  = (const float*)d_in[5];
    const float* W2l  = (const float*)d_in[6];
    const float* b2   = (const float*)d_in[7];
    const float* W2r  = (const float*)d_in[8];
    float* out = (float*)d_out;

    const int N  = in_sizes[0] / IN_CH;
    const int E  = in_sizes[1] / 2;
    const int E2 = in_sizes[2] / 2;
    const int* src = eidx;
    const int* dst = eidx + E;
    const int M    = 2 * N;
    const int NB   = (M + 255) / 256;          // <= 1024
    const int NBUK = (N + 255) / 256;          // coarse buckets (<= 512)

    // ws ints: count[2N] cntG[512] cntP[512] offs[2N] cursor[2N] bsums[1024]
    //          bstartG[512] bcursorG[512] bstartP[512] bcursorP[512] nbr[E]
    int* count    = (int*)d_ws;
    int* cntG     = count + M;
    int* cntP     = cntG + 512;
    int* offs     = cntP + 512;
    int* cursor   = offs + M;
    int* bsums    = cursor + M;
    int* bstartG  = bsums + 1024;
    int* bcursorG = bstartG + 512;
    int* bstartP  = bcursorG + 512;
    int* bcursorP = bstartP + 512;
    int* nbr      = bcursorP + 512;
    size_t intWords = (size_t)3 * M + 1024 + 4 * 512 + 1024 + E;
    intWords = (intWords + 1) & ~(size_t)1;
    unsigned long long* pairs = (unsigned long long*)((int*)d_ws + intWords);
    ushort* xb    = (ushort*)(pairs + E2);
    ushort* agg1b = xb + (size_t)N * IN_CH;
    ushort* agg2b = xb;                        // overlay after gemm1
    ushort* h     = agg1b + (size_t)N * IN_CH;
    ushort* z     = h + (size_t)N * HID;
    ushort* Wt1   = z + (size_t)N * HID;
    ushort* Wt2   = Wt1 + 256 * 256;
    // tmp partition arrays overlay z (dead until gemm2; 32 MB <= 51.2 MB)
    int* tmpD = (int*)z;
    int* tmpS = tmpD + E;
    int* tmpA = tmpS + E;
    unsigned long long* tmpBE = (unsigned long long*)(tmpA + ((E2 + 1) & ~1));

    // ---- conversions ----
    cvt_kernel<<<((N * IN_CH / 4) + 255) / 256, 256, 0, stream>>>(x, xb, N * IN_CH / 4);
    prep_w_kernel<false><<<(256 * 256 + 255) / 256, 256, 0, stream>>>(W1l, W1r, Wt1, IN_CH);
    prep_w_kernel<true><<<(256 * 512 + 255) / 256, 256, 0, stream>>>(W2l, W2r, Wt2, HID);

    // ---- bucketed counting sorts ----
    hipMemsetAsync(count, 0, ((size_t)M + 1024) * sizeof(int), stream);  // count+cntG+cntP
    {
        int Emax = (E > E2) ? E : E2;
        hist2c_kernel<<<(Emax + 255) / 256, 256, 0, stream>>>(dst, edges, count, cntG, cntP, N, E, E2);
        scan1_kernel<<<NB, 256, 0, stream>>>(count, offs, bsums, M);
        scan2_kernel<<<1, 1024, 0, stream>>>(bsums, NB);
        scan3_kernel<<<NB, 256, 0, stream>>>(offs, bsums, cursor, M);
        coarse_scan_kernel<<<1, 512, 0, stream>>>(cntG, cntP, bstartG, bcursorG, bstartP, bcursorP, NBUK);
        partition_g_kernel<<<(E + 256 * PB_VT - 1) / (256 * PB_VT), 256, 0, stream>>>(
            src, dst, bcursorG, tmpD, tmpS, E);
        partition_p_kernel<<<(E2 + 256 * PB_VT - 1) / (256 * PB_VT), 256, 0, stream>>>(
            edges, bcursorP, tmpA, tmpBE, E2);
        fine_scatter_kernel<<<2 * NBUK, 256, 0, stream>>>(
            tmpD, tmpS, tmpA, tmpBE, bstartG, cntG, bstartP, cntP,
            cursor, nbr, pairs, N, E, NBUK);
    }

    // ---- layer 1 ----
    agg1_kernel<<<(N + 3) / 4, 256, 0, stream>>>(xb, nbr, offs, count, agg1b, N);
    sage_gemm_mfma<2 * IN_CH, true><<<(N + 63) / 64, 256, 0, stream>>>(
        agg1b, xb, Wt1, b1, h, N);

    // ---- layer 2 ----
    agg2_kernel<<<(N + 3) / 4, 256, 0, stream>>>(h, nbr, offs, count, agg2b, N);
    sage_gemm_mfma<2 * HID, false><<<(N + 63) / 64, 256, 0, stream>>>(
        agg2b, h, Wt2, b2, z, N);

    // ---- decode ----
    decode2_kernel<<<(N + 3) / 4, 256, 0, stream>>>(z, pairs, offs + N, count + N, out, N, E);
}

// Round 7
// 867.076 us; speedup vs baseline: 1.7368x; 1.7368x over previous
//
#include <hip/hip_runtime.h>

#define IN_CH 128
#define HID   256
#define PB_VT 16            // 4096 edges per partition block

typedef __attribute__((ext_vector_type(8))) short bf16x8;
typedef __attribute__((ext_vector_type(4))) float f32x4;
typedef __attribute__((ext_vector_type(8))) unsigned short ushort8;

__device__ __forceinline__ ushort f2b(float f) {
    unsigned u = __float_as_uint(f);
    unsigned r = (u + 0x7fffu + ((u >> 16) & 1u)) >> 16;
    return (ushort)r;
}
__device__ __forceinline__ float b2f(ushort h) {
    return __uint_as_float(((unsigned)h) << 16);
}

// ================= atomic-free two-level counting sort =================
// Phase A: per-block coarse histograms (LDS atomics only), dense global writes.
__global__ __launch_bounds__(256)
void part_hist_kernel(const int* __restrict__ dst, const int* __restrict__ edges,
                      int* __restrict__ histG, int* __restrict__ histP,
                      int E, int E2, int NBUK, int NBG) {
    __shared__ int hist[512];
    int t = threadIdx.x;
    bool isG = (int)blockIdx.x < NBG;
    int blk = isG ? blockIdx.x : blockIdx.x - NBG;
    for (int i = t; i < NBUK; i += 256) hist[i] = 0;
    __syncthreads();
    long long e0 = (long long)blk * (256 * PB_VT);
    if (isG) {
#pragma unroll
        for (int i = 0; i < PB_VT; i++) {
            long long e = e0 + i * 256 + t;
            if (e < E) atomicAdd(&hist[dst[e] >> 8], 1);
        }
    } else {
#pragma unroll
        for (int i = 0; i < PB_VT; i++) {
            long long e = e0 + i * 256 + t;
            if (e < E2) atomicAdd(&hist[edges[e * 2] >> 8], 1);
        }
    }
    __syncthreads();
    int* outp = isG ? histG : histP;
    for (int i = t; i < NBUK; i += 256) outp[(size_t)blk * NBUK + i] = hist[i];
}

// Phase B1: per-bucket column scan across blocks -> scanT (bucket-major) + totals.
__global__ __launch_bounds__(512)
void col_scan_kernel(const int* __restrict__ histG, const int* __restrict__ histP,
                     int* __restrict__ scanTG, int* __restrict__ scanTP,
                     int* __restrict__ totG, int* __restrict__ totP,
                     int NBUK, int NBG, int NBP) {
    __shared__ int s[512];
    int t = threadIdx.x;
    bool isG = (int)blockIdx.x < NBUK;
    int col = isG ? blockIdx.x : blockIdx.x - NBUK;
    const int* hist = isG ? histG : histP;
    int NBX = isG ? NBG : NBP;
    int v = (t < NBX) ? hist[(size_t)t * NBUK + col] : 0;
    s[t] = v;
    __syncthreads();
    for (int d = 1; d < 512; d <<= 1) {
        int u = (t >= d) ? s[t - d] : 0;
        __syncthreads(); s[t] += u; __syncthreads();
    }
    int* scanT = isG ? scanTG : scanTP;
    if (t < NBX) scanT[(size_t)col * NBX + t] = s[t] - v;
    if (t == 511) (isG ? totG : totP)[col] = s[511];
}

// Phase B2: exclusive scan of bucket totals -> bucket base offsets.
__global__ __launch_bounds__(512)
void bucket_scan_kernel(const int* __restrict__ totG, const int* __restrict__ totP,
                        int* __restrict__ startG, int* __restrict__ startP, int NBUK) {
    __shared__ int s[512];
    int t = threadIdx.x;
    int v = (t < NBUK) ? totG[t] : 0;
    s[t] = v; __syncthreads();
    for (int d = 1; d < 512; d <<= 1) { int u = (t >= d) ? s[t - d] : 0; __syncthreads(); s[t] += u; __syncthreads(); }
    if (t < NBUK) startG[t] = s[t] - v;
    __syncthreads();
    v = (t < NBUK) ? totP[t] : 0;
    s[t] = v; __syncthreads();
    for (int d = 1; d < 512; d <<= 1) { int u = (t >= d) ? s[t - d] : 0; __syncthreads(); s[t] += u; __syncthreads(); }
    if (t < NBUK) startP[t] = s[t] - v;
}

// Phase C: scatter into bucket-contiguous tmp; LDS cursors seeded with exact bases.
__global__ __launch_bounds__(256)
void part_scatter_kernel(const int* __restrict__ src, const int* __restrict__ dst,
                         const int* __restrict__ edges,
                         const int* __restrict__ scanTG, const int* __restrict__ scanTP,
                         const int* __restrict__ startG, const int* __restrict__ startP,
                         int* __restrict__ tmpD, int* __restrict__ tmpS,
                         int* __restrict__ tmpA, unsigned long long* __restrict__ tmpBE,
                         int E, int E2, int NBUK, int NBG, int NBP) {
    __shared__ int cur[512];
    int t = threadIdx.x;
    bool isG = (int)blockIdx.x < NBG;
    int blk = isG ? blockIdx.x : blockIdx.x - NBG;
    int NBX = isG ? NBG : NBP;
    const int* scanT = isG ? scanTG : scanTP;
    const int* bstart = isG ? startG : startP;
    for (int i = t; i < NBUK; i += 256)
        cur[i] = bstart[i] + scanT[(size_t)i * NBX + blk];
    __syncthreads();
    long long e0 = (long long)blk * (256 * PB_VT);
    if (isG) {
#pragma unroll
        for (int i = 0; i < PB_VT; i++) {
            long long e = e0 + i * 256 + t;
            if (e < E) {
                int d = dst[e];
                int pos = atomicAdd(&cur[d >> 8], 1);   // LDS atomic
                tmpD[pos] = d; tmpS[pos] = src[e];
            }
        }
    } else {
#pragma unroll
        for (int i = 0; i < PB_VT; i++) {
            long long e = e0 + i * 256 + t;
            if (e < E2) {
                int2 ab = *(const int2*)(edges + e * 2);
                int pos = atomicAdd(&cur[ab.x >> 8], 1);
                tmpA[pos] = ab.x;
                tmpBE[pos] = ((unsigned long long)(unsigned)ab.y << 32) | (unsigned)e;
            }
        }
    }
}

// Phase D: per-bucket fine sort in LDS; writes count/offs + final nbr/pairs densely.
__global__ __launch_bounds__(256)
void bucket_sort_kernel(const int* __restrict__ tmpD, const int* __restrict__ tmpS,
                        const int* __restrict__ tmpA, const unsigned long long* __restrict__ tmpBE,
                        const int* __restrict__ startG, const int* __restrict__ totG,
                        const int* __restrict__ startP, const int* __restrict__ totP,
                        int* __restrict__ count, int* __restrict__ offs,
                        int* __restrict__ nbr, unsigned long long* __restrict__ pairs,
                        int N, int Npad, int NBUK) {
    __shared__ int h[256], loffs[256], lcur[256];
    int t = threadIdx.x;
    bool isG = (int)blockIdx.x < NBUK;
    int b = isG ? blockIdx.x : blockIdx.x - NBUK;
    int s = isG ? startG[b] : startP[b];
    int c = isG ? totG[b]   : totP[b];
    h[t] = 0;
    __syncthreads();
    const int* keys = isG ? tmpD : tmpA;
    for (int i = t; i < c; i += 256) atomicAdd(&h[keys[s + i] & 255], 1);
    __syncthreads();
    int v = h[t];
    loffs[t] = v;
    __syncthreads();
    for (int d = 1; d < 256; d <<= 1) {
        int u = (t >= d) ? loffs[t - d] : 0;
        __syncthreads(); loffs[t] += u; __syncthreads();
    }
    int excl = loffs[t] - v;
    lcur[t] = excl;
    int node = b * 256 + t;
    if (node < N) {
        int base = isG ? 0 : Npad;
        count[base + node] = v;
        offs[base + node] = s + excl;
    }
    __syncthreads();
    if (isG) {
        for (int i = t; i < c; i += 256) {
            int k = tmpD[s + i] & 255;
            int p = atomicAdd(&lcur[k], 1);
            nbr[s + p] = tmpS[s + i];
        }
    } else {
        for (int i = t; i < c; i += 256) {
            int k = tmpA[s + i] & 255;
            int p = atomicAdd(&lcur[k], 1);
            pairs[s + p] = tmpBE[s + i];
        }
    }
}

// ================= bf16 conversions =================
__global__ void cvt_kernel(const float* __restrict__ in, ushort* __restrict__ o, int n4) {
    int i = blockIdx.x * 256 + threadIdx.x;
    if (i < n4) {
        float4 v = ((const float4*)in)[i];
        ushort4 u;
        u.x = f2b(v.x); u.y = f2b(v.y); u.z = f2b(v.z); u.w = f2b(v.w);
        ((ushort4*)o)[i] = u;
    }
}

template<bool PERM_K>
__global__ void prep_w_kernel(const float* __restrict__ Wl, const float* __restrict__ Wr,
                              ushort* __restrict__ Wt, int KH) {
    int ktot = 2 * KH;
    int idx = blockIdx.x * 256 + threadIdx.x;
    if (idx >= 256 * ktot) return;
    int n = idx / ktot, k = idx % ktot;
    int kh = (k < KH) ? k : (k - KH);
    int c = kh;
    if (PERM_K) {
        int j = kh & 63;
        c = (kh & ~63) | ((j & 3) * 16 + (j >> 2));
    }
    float v = (k < KH) ? Wl[(size_t)c * 256 + n] : Wr[(size_t)c * 256 + n];
    Wt[idx] = f2b(v);
}

// ================= gather-mean aggregation =================
__global__ void agg1_kernel(const ushort* __restrict__ xb, const int* __restrict__ nbr,
                            const int* __restrict__ offs, const int* __restrict__ count,
                            ushort* __restrict__ agg, int N) {
    int w = blockIdx.x * 4 + (threadIdx.x >> 6);
    if (w >= N) return;
    int lane = threadIdx.x & 63;
    int grp = lane >> 4, gl = lane & 15;
    int start = offs[w], cnt = count[w];
    float acc[8];
#pragma unroll
    for (int i = 0; i < 8; i++) acc[i] = 0.0f;
    for (int j = grp; j < cnt; j += 4) {
        int s = nbr[start + j];
        ushort8 v = *(const ushort8*)(xb + (size_t)s * IN_CH + gl * 8);
#pragma unroll
        for (int i = 0; i < 8; i++) acc[i] += b2f(v[i]);
    }
#pragma unroll
    for (int i = 0; i < 8; i++) acc[i] += __shfl_xor(acc[i], 16, 64);
#pragma unroll
    for (int i = 0; i < 8; i++) acc[i] += __shfl_xor(acc[i], 32, 64);
    if (grp == 0) {
        float r = 1.0f / fmaxf((float)cnt, 1.0f);
        ushort8 o;
#pragma unroll
        for (int i = 0; i < 8; i++) o[i] = f2b(acc[i] * r);
        *(ushort8*)(agg + (size_t)w * IN_CH + gl * 8) = o;
    }
}

__global__ void agg2_kernel(const ushort* __restrict__ h, const int* __restrict__ nbr,
                            const int* __restrict__ offs, const int* __restrict__ count,
                            ushort* __restrict__ agg, int N) {
    int w = blockIdx.x * 4 + (threadIdx.x >> 6);
    if (w >= N) return;
    int lane = threadIdx.x & 63;
    int half = lane >> 5, hl = lane & 31;
    int start = offs[w], cnt = count[w];
    float a0[8], a1[8];
#pragma unroll
    for (int i = 0; i < 8; i++) { a0[i] = 0.0f; a1[i] = 0.0f; }
    int j = half;
    for (; j + 2 < cnt; j += 4) {
        int s0 = nbr[start + j];
        int s1 = nbr[start + j + 2];
        ushort8 v0 = *(const ushort8*)(h + (size_t)s0 * HID + hl * 8);
        ushort8 v1 = *(const ushort8*)(h + (size_t)s1 * HID + hl * 8);
#pragma unroll
        for (int i = 0; i < 8; i++) { a0[i] += b2f(v0[i]); a1[i] += b2f(v1[i]); }
    }
    if (j < cnt) {
        int s0 = nbr[start + j];
        ushort8 v0 = *(const ushort8*)(h + (size_t)s0 * HID + hl * 8);
#pragma unroll
        for (int i = 0; i < 8; i++) a0[i] += b2f(v0[i]);
    }
#pragma unroll
    for (int i = 0; i < 8; i++) {
        a0[i] += a1[i];
        a0[i] += __shfl_xor(a0[i], 32, 64);
    }
    if (half == 0) {
        float r = 1.0f / fmaxf((float)cnt, 1.0f);
        ushort8 o;
#pragma unroll
        for (int i = 0; i < 8; i++) o[i] = f2b(a0[i] * r);
        *(ushort8*)(agg + (size_t)w * HID + hl * 8) = o;
    }
}

// ================= MFMA GEMM, permuted coalesced epilogue =================
template<int KTOT, bool RELU>
__global__ __launch_bounds__(256, 2)
void sage_gemm_mfma(const ushort* __restrict__ Aleft, const ushort* __restrict__ Aright,
                    const ushort* __restrict__ Wt, const float* __restrict__ bias,
                    ushort* __restrict__ out, int N) {
    constexpr int KH = KTOT / 2;
    constexpr int LDA = 40;
    __shared__ ushort As[64][LDA];
    __shared__ ushort Bs[256][LDA];

    const int t = threadIdx.x;
    const int wave = t >> 6;
    const int lane = t & 63;
    const int quad = lane >> 4;
    const int l16  = lane & 15;
    const int rowBase = blockIdx.x * 64;

    const int sRow = t >> 2;
    const int sChk = (t & 3) << 3;
    const bool aRowOK = (rowBase + sRow) < N;

    f32x4 acc[4][4];
#pragma unroll
    for (int i = 0; i < 4; i++)
#pragma unroll
        for (int j = 0; j < 4; j++) acc[i][j] = (f32x4)0.0f;

    for (int k0 = 0; k0 < KTOT; k0 += 32) {
        ulonglong2 a16 = {0ull, 0ull};
        if (aRowOK) {
            const ushort* Ap = (k0 < KH)
                ? (Aleft  + (size_t)(rowBase + sRow) * KH + (k0 + sChk))
                : (Aright + (size_t)(rowBase + sRow) * KH + (k0 - KH + sChk));
            a16 = *(const ulonglong2*)Ap;
        }
        ulonglong2 b16[4];
#pragma unroll
        for (int i = 0; i < 4; i++) {
            int n = sRow + i * 64;
            b16[i] = *(const ulonglong2*)(Wt + (size_t)n * KTOT + k0 + sChk);
        }

        __syncthreads();
        *(ulonglong2*)&As[sRow][sChk] = a16;
#pragma unroll
        for (int i = 0; i < 4; i++)
            *(ulonglong2*)&Bs[sRow + i * 64][sChk] = b16[i];
        __syncthreads();

        bf16x8 af[4], bf[4];
#pragma unroll
        for (int mt = 0; mt < 4; mt++)
            af[mt] = *(const bf16x8*)&As[mt * 16 + l16][quad * 8];
#pragma unroll
        for (int nt = 0; nt < 4; nt++)
            bf[nt] = *(const bf16x8*)&Bs[wave * 64 + nt * 16 + l16][quad * 8];
#pragma unroll
        for (int mt = 0; mt < 4; mt++)
#pragma unroll
            for (int nt = 0; nt < 4; nt++)
                acc[mt][nt] = __builtin_amdgcn_mfma_f32_16x16x32_bf16(
                    af[mt], bf[nt], acc[mt][nt], 0, 0, 0);
    }

    float bv[4];
#pragma unroll
    for (int nt = 0; nt < 4; nt++) bv[nt] = bias[wave * 64 + nt * 16 + l16];
#pragma unroll
    for (int mt = 0; mt < 4; mt++) {
#pragma unroll
        for (int reg = 0; reg < 4; reg++) {
            int row = rowBase + mt * 16 + quad * 4 + reg;
            if (row < N) {
                ushort4 o;
                {
                    float v0 = acc[mt][0][reg] + bv[0];
                    float v1 = acc[mt][1][reg] + bv[1];
                    float v2 = acc[mt][2][reg] + bv[2];
                    float v3 = acc[mt][3][reg] + bv[3];
                    if (RELU) {
                        v0 = fmaxf(v0, 0.0f); v1 = fmaxf(v1, 0.0f);
                        v2 = fmaxf(v2, 0.0f); v3 = fmaxf(v3, 0.0f);
                    }
                    o.x = f2b(v0); o.y = f2b(v1); o.z = f2b(v2); o.w = f2b(v3);
                }
                *(ushort4*)(out + (size_t)row * 256 + wave * 64 + l16 * 4) = o;
            }
        }
    }
}

// ================= decode: one wave per a-node over a-sorted pairs =================
__global__ void decode2_kernel(const ushort* __restrict__ z,
                               const unsigned long long* __restrict__ pairs,
                               const int* __restrict__ offsA, const int* __restrict__ countA,
                               float* __restrict__ out, int N) {
    int a = blockIdx.x * 4 + (threadIdx.x >> 6);
    if (a >= N) return;
    int cnt = countA[a];
    if (cnt == 0) return;
    int lane = threadIdx.x & 63;
    int half = lane >> 5, hl = lane & 31;
    int start = offsA[a];

    float ar[8];
    {
        ushort8 va = *(const ushort8*)(z + (size_t)a * HID + hl * 8);
#pragma unroll
        for (int i = 0; i < 8; i++) ar[i] = b2f(va[i]);
    }

    int j = half;
    for (; j + 2 < cnt; j += 4) {
        unsigned long long p0 = pairs[start + j];
        unsigned long long p1 = pairs[start + j + 2];
        int b0 = (int)(p0 >> 32), e0 = (int)(p0 & 0xffffffffu);
        int b1 = (int)(p1 >> 32), e1 = (int)(p1 & 0xffffffffu);
        ushort8 v0 = *(const ushort8*)(z + (size_t)b0 * HID + hl * 8);
        ushort8 v1 = *(const ushort8*)(z + (size_t)b1 * HID + hl * 8);
        float s0 = 0.f, s1 = 0.f;
#pragma unroll
        for (int i = 0; i < 8; i++) { s0 = fmaf(ar[i], b2f(v0[i]), s0);
                                      s1 = fmaf(ar[i], b2f(v1[i]), s1); }
#pragma unroll
        for (int off = 1; off < 32; off <<= 1) { s0 += __shfl_xor(s0, off, 64);
                                                 s1 += __shfl_xor(s1, off, 64); }
        if (hl == 0) { out[e0] = s0; out[e1] = s1; }
    }
    if (j < cnt) {
        unsigned long long p0 = pairs[start + j];
        int b0 = (int)(p0 >> 32), e0 = (int)(p0 & 0xffffffffu);
        ushort8 v0 = *(const ushort8*)(z + (size_t)b0 * HID + hl * 8);
        float s0 = 0.f;
#pragma unroll
        for (int i = 0; i < 8; i++) s0 = fmaf(ar[i], b2f(v0[i]), s0);
#pragma unroll
        for (int off = 1; off < 32; off <<= 1) s0 += __shfl_xor(s0, off, 64);
        if (hl == 0) out[e0] = s0;
    }
}

extern "C" void kernel_launch(void* const* d_in, const int* in_sizes, int n_in,
                              void* d_out, int out_size, void* d_ws, size_t ws_size,
                              hipStream_t stream) {
    const float* x    = (const float*)d_in[0];
    const int* eidx   = (const int*)d_in[1];
    const int* edges  = (const int*)d_in[2];
    const float* W1l  = (const float*)d_in[3];
    const float* b1   = (const float*)d_in[4];
    const float* W1r  = (const float*)d_in[5];
    const float* W2l  = (const float*)d_in[6];
    const float* b2   = (const float*)d_in[7];
    const float* W2r  = (const float*)d_in[8];
    float* out = (float*)d_out;

    const int N  = in_sizes[0] / IN_CH;
    const int E  = in_sizes[1] / 2;
    const int E2 = in_sizes[2] / 2;
    const int* src = eidx;
    const int* dst = eidx + E;

    const int NBUK = (N + 255) >> 8;            // 256-node buckets (<=512)
    const int Npad = NBUK << 8;
    const int NBG  = (E  + 256 * PB_VT - 1) / (256 * PB_VT);   // <=512
    const int NBP  = (E2 + 256 * PB_VT - 1) / (256 * PB_VT);

    // ints: count[2*Npad] offs[2*Npad] histG histP scanTG scanTP tot/start x4 nbr[E]
    int* count   = (int*)d_ws;
    int* offs    = count + 2 * Npad;
    int* histG   = offs + 2 * Npad;
    int* histP   = histG + (size_t)NBG * NBUK;
    int* scanTG  = histP + (size_t)NBP * NBUK;
    int* scanTP  = scanTG + (size_t)NBUK * NBG;
    int* totG    = scanTP + (size_t)NBUK * NBP;
    int* totP    = totG + 512;
    int* startG  = totP + 512;
    int* startP  = startG + 512;
    int* nbr     = startP + 512;
    size_t intWords = (size_t)(nbr - (int*)d_ws) + E;
    intWords = (intWords + 1) & ~(size_t)1;
    unsigned long long* pairs = (unsigned long long*)((int*)d_ws + intWords);
    ushort* xb    = (ushort*)(pairs + E2);
    ushort* agg1b = xb + (size_t)N * IN_CH;
    ushort* agg2b = xb;                         // overlay after gemm1
    ushort* h     = agg1b + (size_t)N * IN_CH;
    ushort* z     = h + (size_t)N * HID;
    ushort* Wt1   = z + (size_t)N * HID;
    ushort* Wt2   = Wt1 + 256 * 256;
    // tmp partition arrays overlay z (dead until gemm2; 32 MB <= 51.2 MB)
    int* tmpD = (int*)z;
    int* tmpS = tmpD + E;
    int* tmpA = tmpS + E;
    unsigned long long* tmpBE = (unsigned long long*)(tmpA + ((E2 + 1) & ~1));

    // ---- conversions ----
    cvt_kernel<<<((N * IN_CH / 4) + 255) / 256, 256, 0, stream>>>(x, xb, N * IN_CH / 4);
    prep_w_kernel<false><<<(256 * 256 + 255) / 256, 256, 0, stream>>>(W1l, W1r, Wt1, IN_CH);
    prep_w_kernel<true><<<(256 * 512 + 255) / 256, 256, 0, stream>>>(W2l, W2r, Wt2, HID);

    // ---- atomic-free two-level counting sorts (graph by dst, candidates by a) ----
    part_hist_kernel<<<NBG + NBP, 256, 0, stream>>>(dst, edges, histG, histP, E, E2, NBUK, NBG);
    col_scan_kernel<<<2 * NBUK, 512, 0, stream>>>(histG, histP, scanTG, scanTP, totG, totP,
                                                  NBUK, NBG, NBP);
    bucket_scan_kernel<<<1, 512, 0, stream>>>(totG, totP, startG, startP, NBUK);
    part_scatter_kernel<<<NBG + NBP, 256, 0, stream>>>(src, dst, edges, scanTG, scanTP,
                                                       startG, startP, tmpD, tmpS, tmpA, tmpBE,
                                                       E, E2, NBUK, NBG, NBP);
    bucket_sort_kernel<<<2 * NBUK, 256, 0, stream>>>(tmpD, tmpS, tmpA, tmpBE,
                                                     startG, totG, startP, totP,
                                                     count, offs, nbr, pairs, N, Npad, NBUK);

    // ---- layer 1 ----
    agg1_kernel<<<(N + 3) / 4, 256, 0, stream>>>(xb, nbr, offs, count, agg1b, N);
    sage_gemm_mfma<2 * IN_CH, true><<<(N + 63) / 64, 256, 0, stream>>>(
        agg1b, xb, Wt1, b1, h, N);

    // ---- layer 2 ----
    agg2_kernel<<<(N + 3) / 4, 256, 0, stream>>>(h, nbr, offs, count, agg2b, N);
    sage_gemm_mfma<2 * HID, false><<<(N + 63) / 64, 256, 0, stream>>>(
        agg2b, h, Wt2, b2, z, N);

    // ---- decode ----
    decode2_kernel<<<(N + 3) / 4, 256, 0, stream>>>(z, pairs, offs + Npad, count + Npad, out, N);
}

// Round 8
// 858.790 us; speedup vs baseline: 1.7535x; 1.0096x over previous
//
#include <hip/hip_runtime.h>

#define IN_CH 128
#define HID   256
#define PB_VT 16            // 4096 edges per partition block

typedef __attribute__((ext_vector_type(8))) short bf16x8;
typedef __attribute__((ext_vector_type(4))) float f32x4;
typedef __attribute__((ext_vector_type(8))) unsigned short ushort8;

__device__ __forceinline__ ushort f2b(float f) {
    unsigned u = __float_as_uint(f);
    unsigned r = (u + 0x7fffu + ((u >> 16) & 1u)) >> 16;
    return (ushort)r;
}
__device__ __forceinline__ float b2f(ushort h) {
    return __uint_as_float(((unsigned)h) << 16);
}

// ================= atomic-free two-level counting sort =================
__global__ __launch_bounds__(256)
void part_hist_kernel(const int* __restrict__ dst, const int* __restrict__ edges,
                      int* __restrict__ histG, int* __restrict__ histP,
                      int E, int E2, int NBUK, int NBG) {
    __shared__ int hist[512];
    int t = threadIdx.x;
    bool isG = (int)blockIdx.x < NBG;
    int blk = isG ? blockIdx.x : blockIdx.x - NBG;
    for (int i = t; i < NBUK; i += 256) hist[i] = 0;
    __syncthreads();
    long long e0 = (long long)blk * (256 * PB_VT);
    if (isG) {
#pragma unroll
        for (int i = 0; i < PB_VT; i++) {
            long long e = e0 + i * 256 + t;
            if (e < E) atomicAdd(&hist[dst[e] >> 8], 1);
        }
    } else {
#pragma unroll
        for (int i = 0; i < PB_VT; i++) {
            long long e = e0 + i * 256 + t;
            if (e < E2) atomicAdd(&hist[edges[e * 2] >> 8], 1);
        }
    }
    __syncthreads();
    int* outp = isG ? histG : histP;
    for (int i = t; i < NBUK; i += 256) outp[(size_t)blk * NBUK + i] = hist[i];
}

__global__ __launch_bounds__(512)
void col_scan_kernel(const int* __restrict__ histG, const int* __restrict__ histP,
                     int* __restrict__ scanTG, int* __restrict__ scanTP,
                     int* __restrict__ totG, int* __restrict__ totP,
                     int NBUK, int NBG, int NBP) {
    __shared__ int s[512];
    int t = threadIdx.x;
    bool isG = (int)blockIdx.x < NBUK;
    int col = isG ? blockIdx.x : blockIdx.x - NBUK;
    const int* hist = isG ? histG : histP;
    int NBX = isG ? NBG : NBP;
    int v = (t < NBX) ? hist[(size_t)t * NBUK + col] : 0;
    s[t] = v;
    __syncthreads();
    for (int d = 1; d < 512; d <<= 1) {
        int u = (t >= d) ? s[t - d] : 0;
        __syncthreads(); s[t] += u; __syncthreads();
    }
    int* scanT = isG ? scanTG : scanTP;
    if (t < NBX) scanT[(size_t)col * NBX + t] = s[t] - v;
    if (t == 511) (isG ? totG : totP)[col] = s[511];
}

__global__ __launch_bounds__(512)
void bucket_scan_kernel(const int* __restrict__ totG, const int* __restrict__ totP,
                        int* __restrict__ startG, int* __restrict__ startP, int NBUK) {
    __shared__ int s[512];
    int t = threadIdx.x;
    int v = (t < NBUK) ? totG[t] : 0;
    s[t] = v; __syncthreads();
    for (int d = 1; d < 512; d <<= 1) { int u = (t >= d) ? s[t - d] : 0; __syncthreads(); s[t] += u; __syncthreads(); }
    if (t < NBUK) startG[t] = s[t] - v;
    __syncthreads();
    v = (t < NBUK) ? totP[t] : 0;
    s[t] = v; __syncthreads();
    for (int d = 1; d < 512; d <<= 1) { int u = (t >= d) ? s[t - d] : 0; __syncthreads(); s[t] += u; __syncthreads(); }
    if (t < NBUK) startP[t] = s[t] - v;
}

__global__ __launch_bounds__(256)
void part_scatter_kernel(const int* __restrict__ src, const int* __restrict__ dst,
                         const int* __restrict__ edges,
                         const int* __restrict__ scanTG, const int* __restrict__ scanTP,
                         const int* __restrict__ startG, const int* __restrict__ startP,
                         int* __restrict__ tmpD, int* __restrict__ tmpS,
                         int* __restrict__ tmpA, unsigned long long* __restrict__ tmpBE,
                         int E, int E2, int NBUK, int NBG, int NBP) {
    __shared__ int cur[512];
    int t = threadIdx.x;
    bool isG = (int)blockIdx.x < NBG;
    int blk = isG ? blockIdx.x : blockIdx.x - NBG;
    int NBX = isG ? NBG : NBP;
    const int* scanT = isG ? scanTG : scanTP;
    const int* bstart = isG ? startG : startP;
    for (int i = t; i < NBUK; i += 256)
        cur[i] = bstart[i] + scanT[(size_t)i * NBX + blk];
    __syncthreads();
    long long e0 = (long long)blk * (256 * PB_VT);
    if (isG) {
#pragma unroll
        for (int i = 0; i < PB_VT; i++) {
            long long e = e0 + i * 256 + t;
            if (e < E) {
                int d = dst[e];
                int pos = atomicAdd(&cur[d >> 8], 1);   // LDS atomic
                tmpD[pos] = d; tmpS[pos] = src[e];
            }
        }
    } else {
#pragma unroll
        for (int i = 0; i < PB_VT; i++) {
            long long e = e0 + i * 256 + t;
            if (e < E2) {
                int2 ab = *(const int2*)(edges + e * 2);
                int pos = atomicAdd(&cur[ab.x >> 8], 1);
                tmpA[pos] = ab.x;
                tmpBE[pos] = ((unsigned long long)(unsigned)ab.y << 32) | (unsigned)e;
            }
        }
    }
}

__global__ __launch_bounds__(256)
void bucket_sort_kernel(const int* __restrict__ tmpD, const int* __restrict__ tmpS,
                        const int* __restrict__ tmpA, const unsigned long long* __restrict__ tmpBE,
                        const int* __restrict__ startG, const int* __restrict__ totG,
                        const int* __restrict__ startP, const int* __restrict__ totP,
                        int* __restrict__ count, int* __restrict__ offs,
                        int* __restrict__ nbr, unsigned long long* __restrict__ pairs,
                        int N, int Npad, int NBUK) {
    __shared__ int h[256], loffs[256], lcur[256];
    int t = threadIdx.x;
    bool isG = (int)blockIdx.x < NBUK;
    int b = isG ? blockIdx.x : blockIdx.x - NBUK;
    int s = isG ? startG[b] : startP[b];
    int c = isG ? totG[b]   : totP[b];
    h[t] = 0;
    __syncthreads();
    const int* keys = isG ? tmpD : tmpA;
    for (int i = t; i < c; i += 256) atomicAdd(&h[keys[s + i] & 255], 1);
    __syncthreads();
    int v = h[t];
    loffs[t] = v;
    __syncthreads();
    for (int d = 1; d < 256; d <<= 1) {
        int u = (t >= d) ? loffs[t - d] : 0;
        __syncthreads(); loffs[t] += u; __syncthreads();
    }
    int excl = loffs[t] - v;
    lcur[t] = excl;
    int node = b * 256 + t;
    if (node < N) {
        int base = isG ? 0 : Npad;
        count[base + node] = v;
        offs[base + node] = s + excl;
    }
    __syncthreads();
    if (isG) {
        for (int i = t; i < c; i += 256) {
            int k = tmpD[s + i] & 255;
            int p = atomicAdd(&lcur[k], 1);
            nbr[s + p] = tmpS[s + i];
        }
    } else {
        for (int i = t; i < c; i += 256) {
            int k = tmpA[s + i] & 255;
            int p = atomicAdd(&lcur[k], 1);
            pairs[s + p] = tmpBE[s + i];
        }
    }
}

// ================= bf16 conversions =================
__global__ void cvt_kernel(const float* __restrict__ in, ushort* __restrict__ o, int n4) {
    int i = blockIdx.x * 256 + threadIdx.x;
    if (i < n4) {
        float4 v = ((const float4*)in)[i];
        ushort4 u;
        u.x = f2b(v.x); u.y = f2b(v.y); u.z = f2b(v.z); u.w = f2b(v.w);
        ((ushort4*)o)[i] = u;
    }
}

template<bool PERM_K>
__global__ void prep_w_kernel(const float* __restrict__ Wl, const float* __restrict__ Wr,
                              ushort* __restrict__ Wt, int KH) {
    int ktot = 2 * KH;
    int idx = blockIdx.x * 256 + threadIdx.x;
    if (idx >= 256 * ktot) return;
    int n = idx / ktot, k = idx % ktot;
    int kh = (k < KH) ? k : (k - KH);
    int c = kh;
    if (PERM_K) {
        int j = kh & 63;
        c = (kh & ~63) | ((j & 3) * 16 + (j >> 2));
    }
    float v = (k < KH) ? Wl[(size_t)c * 256 + n] : Wr[(size_t)c * 256 + n];
    Wt[idx] = f2b(v);
}

// ================= gather-mean aggregation =================
__global__ void agg1_kernel(const ushort* __restrict__ xb, const int* __restrict__ nbr,
                            const int* __restrict__ offs, const int* __restrict__ count,
                            ushort* __restrict__ agg, int N) {
    int w = blockIdx.x * 4 + (threadIdx.x >> 6);
    if (w >= N) return;
    int lane = threadIdx.x & 63;
    int grp = lane >> 4, gl = lane & 15;
    int start = offs[w], cnt = count[w];
    float acc[8];
#pragma unroll
    for (int i = 0; i < 8; i++) acc[i] = 0.0f;
    for (int j = grp; j < cnt; j += 4) {
        int s = nbr[start + j];
        ushort8 v = *(const ushort8*)(xb + (size_t)s * IN_CH + gl * 8);
#pragma unroll
        for (int i = 0; i < 8; i++) acc[i] += b2f(v[i]);
    }
#pragma unroll
    for (int i = 0; i < 8; i++) acc[i] += __shfl_xor(acc[i], 16, 64);
#pragma unroll
    for (int i = 0; i < 8; i++) acc[i] += __shfl_xor(acc[i], 32, 64);
    if (grp == 0) {
        float r = 1.0f / fmaxf((float)cnt, 1.0f);
        ushort8 o;
#pragma unroll
        for (int i = 0; i < 8; i++) o[i] = f2b(acc[i] * r);
        *(ushort8*)(agg + (size_t)w * IN_CH + gl * 8) = o;
    }
}

__global__ void agg2_kernel(const ushort* __restrict__ h, const int* __restrict__ nbr,
                            const int* __restrict__ offs, const int* __restrict__ count,
                            ushort* __restrict__ agg, int N) {
    int w = blockIdx.x * 4 + (threadIdx.x >> 6);
    if (w >= N) return;
    int lane = threadIdx.x & 63;
    int half = lane >> 5, hl = lane & 31;
    int start = offs[w], cnt = count[w];
    float a0[8], a1[8];
#pragma unroll
    for (int i = 0; i < 8; i++) { a0[i] = 0.0f; a1[i] = 0.0f; }
    int j = half;
    for (; j + 2 < cnt; j += 4) {
        int s0 = nbr[start + j];
        int s1 = nbr[start + j + 2];
        ushort8 v0 = *(const ushort8*)(h + (size_t)s0 * HID + hl * 8);
        ushort8 v1 = *(const ushort8*)(h + (size_t)s1 * HID + hl * 8);
#pragma unroll
        for (int i = 0; i < 8; i++) { a0[i] += b2f(v0[i]); a1[i] += b2f(v1[i]); }
    }
    if (j < cnt) {
        int s0 = nbr[start + j];
        ushort8 v0 = *(const ushort8*)(h + (size_t)s0 * HID + hl * 8);
#pragma unroll
        for (int i = 0; i < 8; i++) a0[i] += b2f(v0[i]);
    }
#pragma unroll
    for (int i = 0; i < 8; i++) {
        a0[i] += a1[i];
        a0[i] += __shfl_xor(a0[i], 32, 64);
    }
    if (half == 0) {
        float r = 1.0f / fmaxf((float)cnt, 1.0f);
        ushort8 o;
#pragma unroll
        for (int i = 0; i < 8; i++) o[i] = f2b(a0[i] * r);
        *(ushort8*)(agg + (size_t)w * HID + hl * 8) = o;
    }
}

// ================= MFMA GEMM: fragment-ordered LDS + LDS-bounced epilogue =================
// LDS layout (fragment order): staging thread t's 16B goes to As+t*16B / Bs+(i*256+t)*16B.
// Lane (wave,quad,l16) reads af[mt] at As+(mt*64 + l16*4+quad)*16B -> conflict-free.
// Epilogue: acc -> LDS tile (32 rows x 512B, two halves) -> ushort8 streaming stores
// (each wave instr = 2 complete 512B rows, agg2-style; kills partial-line writebacks).
template<int KTOT, bool RELU>
__global__ __launch_bounds__(256, 2)
void sage_gemm_mfma(const ushort* __restrict__ Aleft, const ushort* __restrict__ Aright,
                    const ushort* __restrict__ Wt, const float* __restrict__ bias,
                    ushort* __restrict__ out, int N) {
    constexpr int KH = KTOT / 2;
    __shared__ ushort smem[2048 + 8192];       // As[2048] | Bs[8192]
    ushort* As = smem;
    ushort* Bs = smem + 2048;

    const int t = threadIdx.x;
    const int wave = t >> 6;
    const int lane = t & 63;
    const int quad = lane >> 4;
    const int l16  = lane & 15;
    const int rowBase = blockIdx.x * 64;

    const int sRow = t >> 2;                   // staging row 0..63
    const int sChk = (t & 3) << 3;             // k-chunk (shorts)
    const bool aRowOK = (rowBase + sRow) < N;

    f32x4 acc[4][4];
#pragma unroll
    for (int i = 0; i < 4; i++)
#pragma unroll
        for (int j = 0; j < 4; j++) acc[i][j] = (f32x4)0.0f;

    for (int k0 = 0; k0 < KTOT; k0 += 32) {
        ulonglong2 a16 = {0ull, 0ull};
        if (aRowOK) {
            const ushort* Ap = (k0 < KH)
                ? (Aleft  + (size_t)(rowBase + sRow) * KH + (k0 + sChk))
                : (Aright + (size_t)(rowBase + sRow) * KH + (k0 - KH + sChk));
            a16 = *(const ulonglong2*)Ap;
        }
        ulonglong2 b16[4];
#pragma unroll
        for (int i = 0; i < 4; i++) {
            int n = sRow + i * 64;
            b16[i] = *(const ulonglong2*)(Wt + (size_t)n * KTOT + k0 + sChk);
        }

        __syncthreads();
        *(ulonglong2*)&As[t * 8] = a16;                       // fragment order
#pragma unroll
        for (int i = 0; i < 4; i++)
            *(ulonglong2*)&Bs[(i * 256 + t) * 8] = b16[i];
        __syncthreads();

        bf16x8 af[4], bf[4];
#pragma unroll
        for (int mt = 0; mt < 4; mt++)
            af[mt] = *(const bf16x8*)&As[(mt * 64 + l16 * 4 + quad) * 8];
#pragma unroll
        for (int nt = 0; nt < 4; nt++)
            bf[nt] = *(const bf16x8*)&Bs[(wave * 256 + nt * 64 + l16 * 4 + quad) * 8];
#pragma unroll
        for (int mt = 0; mt < 4; mt++)
#pragma unroll
            for (int nt = 0; nt < 4; nt++)
                acc[mt][nt] = __builtin_amdgcn_mfma_f32_16x16x32_bf16(
                    af[mt], bf[nt], acc[mt][nt], 0, 0, 0);
    }

    float bv[4];
#pragma unroll
    for (int nt = 0; nt < 4; nt++) bv[nt] = bias[wave * 64 + nt * 16 + l16]; // logical col
    ushort* tile = smem;                       // 32 x 256 shorts = 8192

#pragma unroll
    for (int hf = 0; hf < 2; hf++) {
        __syncthreads();                       // prior LDS use done
#pragma unroll
        for (int mh = 0; mh < 2; mh++) {
            int mt = hf * 2 + mh;
#pragma unroll
            for (int reg = 0; reg < 4; reg++) {
                int rl = mh * 16 + quad * 4 + reg;
                float v0 = acc[mt][0][reg] + bv[0];
                float v1 = acc[mt][1][reg] + bv[1];
                float v2 = acc[mt][2][reg] + bv[2];
                float v3 = acc[mt][3][reg] + bv[3];
                if (RELU) {
                    v0 = fmaxf(v0, 0.0f); v1 = fmaxf(v1, 0.0f);
                    v2 = fmaxf(v2, 0.0f); v3 = fmaxf(v3, 0.0f);
                }
                ushort4 o;
                o.x = f2b(v0); o.y = f2b(v1); o.z = f2b(v2); o.w = f2b(v3);
                // permuted position: cols {nt*16+l16} -> wave*64 + l16*4 + nt
                *(ushort4*)&tile[rl * 256 + wave * 64 + l16 * 4] = o;
            }
        }
        __syncthreads();
#pragma unroll
        for (int i = 0; i < 4; i++) {
            int ch = i * 256 + t;              // 1024 chunks of 16B
            int rl = ch >> 5, c16 = ch & 31;
            int row = rowBase + hf * 32 + rl;
            if (row < N)
                *(ushort8*)(out + (size_t)row * 256 + c16 * 8) =
                    *(const ushort8*)&tile[rl * 256 + c16 * 8];
        }
    }
}

// ================= decode: one wave per a-node over a-sorted pairs =================
__global__ void decode2_kernel(const ushort* __restrict__ z,
                               const unsigned long long* __restrict__ pairs,
                               const int* __restrict__ offsA, const int* __restrict__ countA,
                               float* __restrict__ out, int N) {
    int a = blockIdx.x * 4 + (threadIdx.x >> 6);
    if (a >= N) return;
    int cnt = countA[a];
    if (cnt == 0) return;
    int lane = threadIdx.x & 63;
    int half = lane >> 5, hl = lane & 31;
    int start = offsA[a];

    float ar[8];
    {
        ushort8 va = *(const ushort8*)(z + (size_t)a * HID + hl * 8);
#pragma unroll
        for (int i = 0; i < 8; i++) ar[i] = b2f(va[i]);
    }

    int j = half;
    for (; j + 2 < cnt; j += 4) {
        unsigned long long p0 = pairs[start + j];
        unsigned long long p1 = pairs[start + j + 2];
        int b0 = (int)(p0 >> 32), e0 = (int)(p0 & 0xffffffffu);
        int b1 = (int)(p1 >> 32), e1 = (int)(p1 & 0xffffffffu);
        ushort8 v0 = *(const ushort8*)(z + (size_t)b0 * HID + hl * 8);
        ushort8 v1 = *(const ushort8*)(z + (size_t)b1 * HID + hl * 8);
        float s0 = 0.f, s1 = 0.f;
#pragma unroll
        for (int i = 0; i < 8; i++) { s0 = fmaf(ar[i], b2f(v0[i]), s0);
                                      s1 = fmaf(ar[i], b2f(v1[i]), s1); }
#pragma unroll
        for (int off = 1; off < 32; off <<= 1) { s0 += __shfl_xor(s0, off, 64);
                                                 s1 += __shfl_xor(s1, off, 64); }
        if (hl == 0) { out[e0] = s0; out[e1] = s1; }
    }
    if (j < cnt) {
        unsigned long long p0 = pairs[start + j];
        int b0 = (int)(p0 >> 32), e0 = (int)(p0 & 0xffffffffu);
        ushort8 v0 = *(const ushort8*)(z + (size_t)b0 * HID + hl * 8);
        float s0 = 0.f;
#pragma unroll
        for (int i = 0; i < 8; i++) s0 = fmaf(ar[i], b2f(v0[i]), s0);
#pragma unroll
        for (int off = 1; off < 32; off <<= 1) s0 += __shfl_xor(s0, off, 64);
        if (hl == 0) out[e0] = s0;
    }
}

extern "C" void kernel_launch(void* const* d_in, const int* in_sizes, int n_in,
                              void* d_out, int out_size, void* d_ws, size_t ws_size,
                              hipStream_t stream) {
    const float* x    = (const float*)d_in[0];
    const int* eidx   = (const int*)d_in[1];
    const int* edges  = (const int*)d_in[2];
    const float* W1l  = (const float*)d_in[3];
    const float* b1   = (const float*)d_in[4];
    const float* W1r  = (const float*)d_in[5];
    const float* W2l  = (const float*)d_in[6];
    const float* b2   = (const float*)d_in[7];
    const float* W2r  = (const float*)d_in[8];
    float* out = (float*)d_out;

    const int N  = in_sizes[0] / IN_CH;
    const int E  = in_sizes[1] / 2;
    const int E2 = in_sizes[2] / 2;
    const int* src = eidx;
    const int* dst = eidx + E;

    const int NBUK = (N + 255) >> 8;            // 256-node buckets (<=512)
    const int Npad = NBUK << 8;
    const int NBG  = (E  + 256 * PB_VT - 1) / (256 * PB_VT);   // <=512
    const int NBP  = (E2 + 256 * PB_VT - 1) / (256 * PB_VT);

    int* count   = (int*)d_ws;
    int* offs    = count + 2 * Npad;
    int* histG   = offs + 2 * Npad;
    int* histP   = histG + (size_t)NBG * NBUK;
    int* scanTG  = histP + (size_t)NBP * NBUK;
    int* scanTP  = scanTG + (size_t)NBUK * NBG;
    int* totG    = scanTP + (size_t)NBUK * NBP;
    int* totP    = totG + 512;
    int* startG  = totP + 512;
    int* startP  = startG + 512;
    int* nbr     = startP + 512;
    size_t intWords = (size_t)(nbr - (int*)d_ws) + E;
    intWords = (intWords + 1) & ~(size_t)1;
    unsigned long long* pairs = (unsigned long long*)((int*)d_ws + intWords);
    ushort* xb    = (ushort*)(pairs + E2);
    ushort* agg1b = xb + (size_t)N * IN_CH;
    ushort* agg2b = xb;                         // overlay after gemm1
    ushort* h     = agg1b + (size_t)N * IN_CH;
    ushort* z     = h + (size_t)N * HID;
    ushort* Wt1   = z + (size_t)N * HID;
    ushort* Wt2   = Wt1 + 256 * 256;
    // tmp partition arrays overlay z (dead until gemm2)
    int* tmpD = (int*)z;
    int* tmpS = tmpD + E;
    int* tmpA = tmpS + E;
    unsigned long long* tmpBE = (unsigned long long*)(tmpA + ((E2 + 1) & ~1));

    // ---- conversions ----
    cvt_kernel<<<((N * IN_CH / 4) + 255) / 256, 256, 0, stream>>>(x, xb, N * IN_CH / 4);
    prep_w_kernel<false><<<(256 * 256 + 255) / 256, 256, 0, stream>>>(W1l, W1r, Wt1, IN_CH);
    prep_w_kernel<true><<<(256 * 512 + 255) / 256, 256, 0, stream>>>(W2l, W2r, Wt2, HID);

    // ---- atomic-free two-level counting sorts ----
    part_hist_kernel<<<NBG + NBP, 256, 0, stream>>>(dst, edges, histG, histP, E, E2, NBUK, NBG);
    col_scan_kernel<<<2 * NBUK, 512, 0, stream>>>(histG, histP, scanTG, scanTP, totG, totP,
                                                  NBUK, NBG, NBP);
    bucket_scan_kernel<<<1, 512, 0, stream>>>(totG, totP, startG, startP, NBUK);
    part_scatter_kernel<<<NBG + NBP, 256, 0, stream>>>(src, dst, edges, scanTG, scanTP,
                                                       startG, startP, tmpD, tmpS, tmpA, tmpBE,
                                                       E, E2, NBUK, NBG, NBP);
    bucket_sort_kernel<<<2 * NBUK, 256, 0, stream>>>(tmpD, tmpS, tmpA, tmpBE,
                                                     startG, totG, startP, totP,
                                                     count, offs, nbr, pairs, N, Npad, NBUK);

    // ---- layer 1 ----
    agg1_kernel<<<(N + 3) / 4, 256, 0, stream>>>(xb, nbr, offs, count, agg1b, N);
    sage_gemm_mfma<2 * IN_CH, true><<<(N + 63) / 64, 256, 0, stream>>>(
        agg1b, xb, Wt1, b1, h, N);

    // ---- layer 2 ----
    agg2_kernel<<<(N + 3) / 4, 256, 0, stream>>>(h, nbr, offs, count, agg2b, N);
    sage_gemm_mfma<2 * HID, false><<<(N + 63) / 64, 256, 0, stream>>>(
        agg2b, h, Wt2, b2, z, N);

    // ---- decode ----
    decode2_kernel<<<(N + 3) / 4, 256, 0, stream>>>(z, pairs, offs + Npad, count + Npad, out, N);
}

// Round 9
// 819.259 us; speedup vs baseline: 1.8381x; 1.0483x over previous
//
#include <hip/hip_runtime.h>

#define IN_CH 128
#define HID   256
#define PB_VT 16            // 4096 edges per partition block

typedef __attribute__((ext_vector_type(8))) short bf16x8;
typedef __attribute__((ext_vector_type(4))) float f32x4;
typedef __attribute__((ext_vector_type(8))) unsigned short ushort8;

__device__ __forceinline__ ushort f2b(float f) {
    unsigned u = __float_as_uint(f);
    unsigned r = (u + 0x7fffu + ((u >> 16) & 1u)) >> 16;
    return (ushort)r;
}
__device__ __forceinline__ float b2f(ushort h) {
    return __uint_as_float(((unsigned)h) << 16);
}

// ================= atomic-free two-level counting sort =================
__global__ __launch_bounds__(256)
void part_hist_kernel(const int* __restrict__ dst, const int* __restrict__ edges,
                      int* __restrict__ histG, int* __restrict__ histP,
                      int E, int E2, int NBUK, int NBG) {
    __shared__ int hist[512];
    int t = threadIdx.x;
    bool isG = (int)blockIdx.x < NBG;
    int blk = isG ? blockIdx.x : blockIdx.x - NBG;
    for (int i = t; i < NBUK; i += 256) hist[i] = 0;
    __syncthreads();
    long long e0 = (long long)blk * (256 * PB_VT);
    if (isG) {
#pragma unroll
        for (int i = 0; i < PB_VT; i++) {
            long long e = e0 + i * 256 + t;
            if (e < E) atomicAdd(&hist[dst[e] >> 8], 1);
        }
    } else {
#pragma unroll
        for (int i = 0; i < PB_VT; i++) {
            long long e = e0 + i * 256 + t;
            if (e < E2) atomicAdd(&hist[edges[e * 2] >> 8], 1);
        }
    }
    __syncthreads();
    int* outp = isG ? histG : histP;
    for (int i = t; i < NBUK; i += 256) outp[(size_t)blk * NBUK + i] = hist[i];
}

__global__ __launch_bounds__(512)
void col_scan_kernel(const int* __restrict__ histG, const int* __restrict__ histP,
                     int* __restrict__ scanTG, int* __restrict__ scanTP,
                     int* __restrict__ totG, int* __restrict__ totP,
                     int NBUK, int NBG, int NBP) {
    __shared__ int s[512];
    int t = threadIdx.x;
    bool isG = (int)blockIdx.x < NBUK;
    int col = isG ? blockIdx.x : blockIdx.x - NBUK;
    const int* hist = isG ? histG : histP;
    int NBX = isG ? NBG : NBP;
    int v = (t < NBX) ? hist[(size_t)t * NBUK + col] : 0;
    s[t] = v;
    __syncthreads();
    for (int d = 1; d < 512; d <<= 1) {
        int u = (t >= d) ? s[t - d] : 0;
        __syncthreads(); s[t] += u; __syncthreads();
    }
    int* scanT = isG ? scanTG : scanTP;
    if (t < NBX) scanT[(size_t)col * NBX + t] = s[t] - v;
    if (t == 511) (isG ? totG : totP)[col] = s[511];
}

__global__ __launch_bounds__(512)
void bucket_scan_kernel(const int* __restrict__ totG, const int* __restrict__ totP,
                        int* __restrict__ startG, int* __restrict__ startP, int NBUK) {
    __shared__ int s[512];
    int t = threadIdx.x;
    int v = (t < NBUK) ? totG[t] : 0;
    s[t] = v; __syncthreads();
    for (int d = 1; d < 512; d <<= 1) { int u = (t >= d) ? s[t - d] : 0; __syncthreads(); s[t] += u; __syncthreads(); }
    if (t < NBUK) startG[t] = s[t] - v;
    __syncthreads();
    v = (t < NBUK) ? totP[t] : 0;
    s[t] = v; __syncthreads();
    for (int d = 1; d < 512; d <<= 1) { int u = (t >= d) ? s[t - d] : 0; __syncthreads(); s[t] += u; __syncthreads(); }
    if (t < NBUK) startP[t] = s[t] - v;
}

// Phase C: scatter into bucket-contiguous tmp (packed payloads).
// graph: u32 = (src<<8) | (dst&255).  pairs: u64 = (a8<<56) | (b<<32) | e.
__global__ __launch_bounds__(256)
void part_scatter_kernel(const int* __restrict__ src, const int* __restrict__ dst,
                         const int* __restrict__ edges,
                         const int* __restrict__ scanTG, const int* __restrict__ scanTP,
                         const int* __restrict__ startG, const int* __restrict__ startP,
                         unsigned* __restrict__ tmpG, unsigned long long* __restrict__ tmpP,
                         int E, int E2, int NBUK, int NBG, int NBP) {
    __shared__ int cur[512];
    int t = threadIdx.x;
    bool isG = (int)blockIdx.x < NBG;
    int blk = isG ? blockIdx.x : blockIdx.x - NBG;
    int NBX = isG ? NBG : NBP;
    const int* scanT = isG ? scanTG : scanTP;
    const int* bstart = isG ? startG : startP;
    for (int i = t; i < NBUK; i += 256)
        cur[i] = bstart[i] + scanT[(size_t)i * NBX + blk];
    __syncthreads();
    long long e0 = (long long)blk * (256 * PB_VT);
    if (isG) {
#pragma unroll
        for (int i = 0; i < PB_VT; i++) {
            long long e = e0 + i * 256 + t;
            if (e < E) {
                int d = dst[e];
                int pos = atomicAdd(&cur[d >> 8], 1);   // LDS atomic
                tmpG[pos] = ((unsigned)src[e] << 8) | (unsigned)(d & 255);
            }
        }
    } else {
#pragma unroll
        for (int i = 0; i < PB_VT; i++) {
            long long e = e0 + i * 256 + t;
            if (e < E2) {
                int2 ab = *(const int2*)(edges + e * 2);
                int pos = atomicAdd(&cur[ab.x >> 8], 1);
                tmpP[pos] = ((unsigned long long)(unsigned)(ab.x & 255) << 56)
                          | ((unsigned long long)(unsigned)ab.y << 32)
                          | (unsigned)e;
            }
        }
    }
}

__global__ __launch_bounds__(256)
void bucket_sort_kernel(const unsigned* __restrict__ tmpG, const unsigned long long* __restrict__ tmpP,
                        const int* __restrict__ startG, const int* __restrict__ totG,
                        const int* __restrict__ startP, const int* __restrict__ totP,
                        int* __restrict__ count, int* __restrict__ offs,
                        int* __restrict__ nbr, unsigned long long* __restrict__ pairs,
                        int N, int Npad, int NBUK) {
    __shared__ int h[256], loffs[256], lcur[256];
    int t = threadIdx.x;
    bool isG = (int)blockIdx.x < NBUK;
    int b = isG ? blockIdx.x : blockIdx.x - NBUK;
    int s = isG ? startG[b] : startP[b];
    int c = isG ? totG[b]   : totP[b];
    h[t] = 0;
    __syncthreads();
    if (isG) {
        for (int i = t; i < c; i += 256) atomicAdd(&h[tmpG[s + i] & 255], 1);
    } else {
        for (int i = t; i < c; i += 256) atomicAdd(&h[(int)(tmpP[s + i] >> 56)], 1);
    }
    __syncthreads();
    int v = h[t];
    loffs[t] = v;
    __syncthreads();
    for (int d = 1; d < 256; d <<= 1) {
        int u = (t >= d) ? loffs[t - d] : 0;
        __syncthreads(); loffs[t] += u; __syncthreads();
    }
    int excl = loffs[t] - v;
    lcur[t] = excl;
    int node = b * 256 + t;
    if (node < N) {
        int base = isG ? 0 : Npad;
        count[base + node] = v;
        offs[base + node] = s + excl;
    }
    __syncthreads();
    if (isG) {
        for (int i = t; i < c; i += 256) {
            unsigned w = tmpG[s + i];
            int p = atomicAdd(&lcur[w & 255], 1);
            nbr[s + p] = (int)(w >> 8);
        }
    } else {
        for (int i = t; i < c; i += 256) {
            unsigned long long w = tmpP[s + i];
            int p = atomicAdd(&lcur[(int)(w >> 56)], 1);
            pairs[s + p] = w & 0x00FFFFFFFFFFFFFFull;
        }
    }
}

// ================= bf16 conversions =================
__global__ void cvt_kernel(const float* __restrict__ in, ushort* __restrict__ o, int n4) {
    int i = blockIdx.x * 256 + threadIdx.x;
    if (i < n4) {
        float4 v = ((const float4*)in)[i];
        ushort4 u;
        u.x = f2b(v.x); u.y = f2b(v.y); u.z = f2b(v.z); u.w = f2b(v.w);
        ((ushort4*)o)[i] = u;
    }
}

template<bool PERM_K>
__global__ void prep_w_kernel(const float* __restrict__ Wl, const float* __restrict__ Wr,
                              ushort* __restrict__ Wt, int KH) {
    int ktot = 2 * KH;
    int idx = blockIdx.x * 256 + threadIdx.x;
    if (idx >= 256 * ktot) return;
    int n = idx / ktot, k = idx % ktot;
    int kh = (k < KH) ? k : (k - KH);
    int c = kh;
    if (PERM_K) {
        int j = kh & 63;
        c = (kh & ~63) | ((j & 3) * 16 + (j >> 2));
    }
    float v = (k < KH) ? Wl[(size_t)c * 256 + n] : Wr[(size_t)c * 256 + n];
    Wt[idx] = f2b(v);
}

// ================= gather-mean aggregation =================
__global__ void agg1_kernel(const ushort* __restrict__ xb, const int* __restrict__ nbr,
                            const int* __restrict__ offs, const int* __restrict__ count,
                            ushort* __restrict__ agg, int N) {
    int w = blockIdx.x * 4 + (threadIdx.x >> 6);
    if (w >= N) return;
    int lane = threadIdx.x & 63;
    int grp = lane >> 4, gl = lane & 15;
    int start = offs[w], cnt = count[w];
    float a0[8], a1[8];
#pragma unroll
    for (int i = 0; i < 8; i++) { a0[i] = 0.0f; a1[i] = 0.0f; }
    int j = grp;
    for (; j + 4 < cnt; j += 8) {
        int s0 = nbr[start + j];
        int s1 = nbr[start + j + 4];
        ushort8 v0 = *(const ushort8*)(xb + (size_t)s0 * IN_CH + gl * 8);
        ushort8 v1 = *(const ushort8*)(xb + (size_t)s1 * IN_CH + gl * 8);
#pragma unroll
        for (int i = 0; i < 8; i++) { a0[i] += b2f(v0[i]); a1[i] += b2f(v1[i]); }
    }
    if (j < cnt) {
        int s0 = nbr[start + j];
        ushort8 v0 = *(const ushort8*)(xb + (size_t)s0 * IN_CH + gl * 8);
#pragma unroll
        for (int i = 0; i < 8; i++) a0[i] += b2f(v0[i]);
    }
#pragma unroll
    for (int i = 0; i < 8; i++) {
        a0[i] += a1[i];
        a0[i] += __shfl_xor(a0[i], 16, 64);
        a0[i] += __shfl_xor(a0[i], 32, 64);
    }
    if (grp == 0) {
        float r = 1.0f / fmaxf((float)cnt, 1.0f);
        ushort8 o;
#pragma unroll
        for (int i = 0; i < 8; i++) o[i] = f2b(a0[i] * r);
        *(ushort8*)(agg + (size_t)w * IN_CH + gl * 8) = o;
    }
}

__global__ void agg2_kernel(const ushort* __restrict__ h, const int* __restrict__ nbr,
                            const int* __restrict__ offs, const int* __restrict__ count,
                            ushort* __restrict__ agg, int N) {
    int w = blockIdx.x * 4 + (threadIdx.x >> 6);
    if (w >= N) return;
    int lane = threadIdx.x & 63;
    int half = lane >> 5, hl = lane & 31;
    int start = offs[w], cnt = count[w];
    float a0[8], a1[8];
#pragma unroll
    for (int i = 0; i < 8; i++) { a0[i] = 0.0f; a1[i] = 0.0f; }
    int j = half;
    for (; j + 6 < cnt; j += 8) {
        int s0 = nbr[start + j];
        int s1 = nbr[start + j + 2];
        int s2 = nbr[start + j + 4];
        int s3 = nbr[start + j + 6];
        ushort8 v0 = *(const ushort8*)(h + (size_t)s0 * HID + hl * 8);
        ushort8 v1 = *(const ushort8*)(h + (size_t)s1 * HID + hl * 8);
        ushort8 v2 = *(const ushort8*)(h + (size_t)s2 * HID + hl * 8);
        ushort8 v3 = *(const ushort8*)(h + (size_t)s3 * HID + hl * 8);
#pragma unroll
        for (int i = 0; i < 8; i++) {
            a0[i] += b2f(v0[i]) + b2f(v2[i]);
            a1[i] += b2f(v1[i]) + b2f(v3[i]);
        }
    }
    for (; j < cnt; j += 2) {
        int s0 = nbr[start + j];
        ushort8 v0 = *(const ushort8*)(h + (size_t)s0 * HID + hl * 8);
#pragma unroll
        for (int i = 0; i < 8; i++) a0[i] += b2f(v0[i]);
    }
#pragma unroll
    for (int i = 0; i < 8; i++) {
        a0[i] += a1[i];
        a0[i] += __shfl_xor(a0[i], 32, 64);
    }
    if (half == 0) {
        float r = 1.0f / fmaxf((float)cnt, 1.0f);
        ushort8 o;
#pragma unroll
        for (int i = 0; i < 8; i++) o[i] = f2b(a0[i] * r);
        *(ushort8*)(agg + (size_t)w * HID + hl * 8) = o;
    }
}

// ================= MFMA GEMM: software-pipelined K-loop =================
// Prefetch k+1's global loads right after writing k's LDS tiles so HBM latency
// overlaps MFMA + ds_read instead of stalling at the LDS write.
template<int KTOT, bool RELU>
__global__ __launch_bounds__(256, 2)
void sage_gemm_mfma(const ushort* __restrict__ Aleft, const ushort* __restrict__ Aright,
                    const ushort* __restrict__ Wt, const float* __restrict__ bias,
                    ushort* __restrict__ out, int N) {
    constexpr int KH = KTOT / 2;
    __shared__ ushort smem[2048 + 8192];       // As[2048] | Bs[8192]
    ushort* As = smem;
    ushort* Bs = smem + 2048;

    const int t = threadIdx.x;
    const int wave = t >> 6;
    const int lane = t & 63;
    const int quad = lane >> 4;
    const int l16  = lane & 15;
    const int rowBase = blockIdx.x * 64;

    const int sRow = t >> 2;                   // staging row 0..63
    const int sChk = (t & 3) << 3;             // k-chunk (shorts)
    const bool aRowOK = (rowBase + sRow) < N;

    f32x4 acc[4][4];
#pragma unroll
    for (int i = 0; i < 4; i++)
#pragma unroll
        for (int j = 0; j < 4; j++) acc[i][j] = (f32x4)0.0f;

    // prefetch k0 = 0
    ulonglong2 a16 = {0ull, 0ull};
    ulonglong2 b16[4];
    {
        if (aRowOK)
            a16 = *(const ulonglong2*)(Aleft + (size_t)(rowBase + sRow) * KH + sChk);
#pragma unroll
        for (int i = 0; i < 4; i++)
            b16[i] = *(const ulonglong2*)(Wt + (size_t)(sRow + i * 64) * KTOT + sChk);
    }

    for (int k0 = 0; k0 < KTOT; k0 += 32) {
        __syncthreads();                       // prior ds_reads done
        *(ulonglong2*)&As[t * 8] = a16;        // waits on prefetched loads
#pragma unroll
        for (int i = 0; i < 4; i++)
            *(ulonglong2*)&Bs[(i * 256 + t) * 8] = b16[i];

        int kn = k0 + 32;
        if (kn < KTOT) {                       // issue next prefetch (latency hidden)
            if (aRowOK) {
                const ushort* Ap = (kn < KH)
                    ? (Aleft  + (size_t)(rowBase + sRow) * KH + (kn + sChk))
                    : (Aright + (size_t)(rowBase + sRow) * KH + (kn - KH + sChk));
                a16 = *(const ulonglong2*)Ap;
            }
#pragma unroll
            for (int i = 0; i < 4; i++)
                b16[i] = *(const ulonglong2*)(Wt + (size_t)(sRow + i * 64) * KTOT + kn + sChk);
        }
        __syncthreads();

        bf16x8 af[4], bf[4];
#pragma unroll
        for (int mt = 0; mt < 4; mt++)
            af[mt] = *(const bf16x8*)&As[(mt * 64 + l16 * 4 + quad) * 8];
#pragma unroll
        for (int nt = 0; nt < 4; nt++)
            bf[nt] = *(const bf16x8*)&Bs[(wave * 256 + nt * 64 + l16 * 4 + quad) * 8];
#pragma unroll
        for (int mt = 0; mt < 4; mt++)
#pragma unroll
            for (int nt = 0; nt < 4; nt++)
                acc[mt][nt] = __builtin_amdgcn_mfma_f32_16x16x32_bf16(
                    af[mt], bf[nt], acc[mt][nt], 0, 0, 0);
    }

    float bv[4];
#pragma unroll
    for (int nt = 0; nt < 4; nt++) bv[nt] = bias[wave * 64 + nt * 16 + l16]; // logical col
    ushort* tile = smem;                       // 32 x 256 shorts

#pragma unroll
    for (int hf = 0; hf < 2; hf++) {
        __syncthreads();
#pragma unroll
        for (int mh = 0; mh < 2; mh++) {
            int mt = hf * 2 + mh;
#pragma unroll
            for (int reg = 0; reg < 4; reg++) {
                int rl = mh * 16 + quad * 4 + reg;
                float v0 = acc[mt][0][reg] + bv[0];
                float v1 = acc[mt][1][reg] + bv[1];
                float v2 = acc[mt][2][reg] + bv[2];
                float v3 = acc[mt][3][reg] + bv[3];
                if (RELU) {
                    v0 = fmaxf(v0, 0.0f); v1 = fmaxf(v1, 0.0f);
                    v2 = fmaxf(v2, 0.0f); v3 = fmaxf(v3, 0.0f);
                }
                ushort4 o;
                o.x = f2b(v0); o.y = f2b(v1); o.z = f2b(v2); o.w = f2b(v3);
                *(ushort4*)&tile[rl * 256 + wave * 64 + l16 * 4] = o;
            }
        }
        __syncthreads();
#pragma unroll
        for (int i = 0; i < 4; i++) {
            int ch = i * 256 + t;
            int rl = ch >> 5, c16 = ch & 31;
            int row = rowBase + hf * 32 + rl;
            if (row < N)
                *(ushort8*)(out + (size_t)row * 256 + c16 * 8) =
                    *(const ushort8*)&tile[rl * 256 + c16 * 8];
        }
    }
}

// ================= decode: one wave per a-node, 4-deep per half =================
__global__ void decode2_kernel(const ushort* __restrict__ z,
                               const unsigned long long* __restrict__ pairs,
                               const int* __restrict__ offsA, const int* __restrict__ countA,
                               float* __restrict__ out, int N) {
    int a = blockIdx.x * 4 + (threadIdx.x >> 6);
    if (a >= N) return;
    int cnt = countA[a];
    if (cnt == 0) return;
    int lane = threadIdx.x & 63;
    int half = lane >> 5, hl = lane & 31;
    int start = offsA[a];

    float ar[8];
    {
        ushort8 va = *(const ushort8*)(z + (size_t)a * HID + hl * 8);
#pragma unroll
        for (int i = 0; i < 8; i++) ar[i] = b2f(va[i]);
    }

    int j = half;
    for (; j + 6 < cnt; j += 8) {
        unsigned long long p0 = pairs[start + j];
        unsigned long long p1 = pairs[start + j + 2];
        unsigned long long p2 = pairs[start + j + 4];
        unsigned long long p3 = pairs[start + j + 6];
        int b0 = (int)(p0 >> 32), e0 = (int)(p0 & 0xffffffffu);
        int b1 = (int)(p1 >> 32), e1 = (int)(p1 & 0xffffffffu);
        int b2 = (int)(p2 >> 32), e2 = (int)(p2 & 0xffffffffu);
        int b3 = (int)(p3 >> 32), e3 = (int)(p3 & 0xffffffffu);
        ushort8 v0 = *(const ushort8*)(z + (size_t)b0 * HID + hl * 8);
        ushort8 v1 = *(const ushort8*)(z + (size_t)b1 * HID + hl * 8);
        ushort8 v2 = *(const ushort8*)(z + (size_t)b2 * HID + hl * 8);
        ushort8 v3 = *(const ushort8*)(z + (size_t)b3 * HID + hl * 8);
        float s0 = 0.f, s1 = 0.f, s2 = 0.f, s3 = 0.f;
#pragma unroll
        for (int i = 0; i < 8; i++) {
            s0 = fmaf(ar[i], b2f(v0[i]), s0);
            s1 = fmaf(ar[i], b2f(v1[i]), s1);
            s2 = fmaf(ar[i], b2f(v2[i]), s2);
            s3 = fmaf(ar[i], b2f(v3[i]), s3);
        }
#pragma unroll
        for (int off = 1; off < 32; off <<= 1) {
            s0 += __shfl_xor(s0, off, 64);
            s1 += __shfl_xor(s1, off, 64);
            s2 += __shfl_xor(s2, off, 64);
            s3 += __shfl_xor(s3, off, 64);
        }
        if (hl == 0) { out[e0] = s0; out[e1] = s1; out[e2] = s2; out[e3] = s3; }
    }
    for (; j < cnt; j += 2) {
        unsigned long long p0 = pairs[start + j];
        int b0 = (int)(p0 >> 32), e0 = (int)(p0 & 0xffffffffu);
        ushort8 v0 = *(const ushort8*)(z + (size_t)b0 * HID + hl * 8);
        float s0 = 0.f;
#pragma unroll
        for (int i = 0; i < 8; i++) s0 = fmaf(ar[i], b2f(v0[i]), s0);
#pragma unroll
        for (int off = 1; off < 32; off <<= 1) s0 += __shfl_xor(s0, off, 64);
        if (hl == 0) out[e0] = s0;
    }
}

extern "C" void kernel_launch(void* const* d_in, const int* in_sizes, int n_in,
                              void* d_out, int out_size, void* d_ws, size_t ws_size,
                              hipStream_t stream) {
    const float* x    = (const float*)d_in[0];
    const int* eidx   = (const int*)d_in[1];
    const int* edges  = (const int*)d_in[2];
    const float* W1l  = (const float*)d_in[3];
    const float* b1   = (const float*)d_in[4];
    const float* W1r  = (const float*)d_in[5];
    const float* W2l  = (const float*)d_in[6];
    const float* b2   = (const float*)d_in[7];
    const float* W2r  = (const float*)d_in[8];
    float* out = (float*)d_out;

    const int N  = in_sizes[0] / IN_CH;
    const int E  = in_sizes[1] / 2;
    const int E2 = in_sizes[2] / 2;
    const int* src = eidx;
    const int* dst = eidx + E;

    const int NBUK = (N + 255) >> 8;            // 256-node buckets (<=512)
    const int Npad = NBUK << 8;
    const int NBG  = (E  + 256 * PB_VT - 1) / (256 * PB_VT);   // <=512
    const int NBP  = (E2 + 256 * PB_VT - 1) / (256 * PB_VT);

    int* count   = (int*)d_ws;
    int* offs    = count + 2 * Npad;
    int* histG   = offs + 2 * Npad;
    int* histP   = histG + (size_t)NBG * NBUK;
    int* scanTG  = histP + (size_t)NBP * NBUK;
    int* scanTP  = scanTG + (size_t)NBUK * NBG;
    int* totG    = scanTP + (size_t)NBUK * NBP;
    int* totP    = totG + 512;
    int* startG  = totP + 512;
    int* startP  = startG + 512;
    int* nbr     = startP + 512;
    size_t intWords = (size_t)(nbr - (int*)d_ws) + E;
    intWords = (intWords + 1) & ~(size_t)1;
    unsigned long long* pairs = (unsigned long long*)((int*)d_ws + intWords);
    ushort* xb    = (ushort*)(pairs + E2);
    ushort* agg1b = xb + (size_t)N * IN_CH;
    ushort* agg2b = xb;                         // overlay after gemm1
    ushort* h     = agg1b + (size_t)N * IN_CH;
    ushort* z     = h + (size_t)N * HID;
    ushort* Wt1   = z + (size_t)N * HID;
    ushort* Wt2   = Wt1 + 256 * 256;
    // packed tmp partition arrays overlay z (dead until gemm2; 19.2 MB <= 51.2 MB)
    unsigned* tmpG = (unsigned*)z;
    unsigned long long* tmpP = (unsigned long long*)(tmpG + ((E + 1) & ~1));

    // ---- conversions ----
    cvt_kernel<<<((N * IN_CH / 4) + 255) / 256, 256, 0, stream>>>(x, xb, N * IN_CH / 4);
    prep_w_kernel<false><<<(256 * 256 + 255) / 256, 256, 0, stream>>>(W1l, W1r, Wt1, IN_CH);
    prep_w_kernel<true><<<(256 * 512 + 255) / 256, 256, 0, stream>>>(W2l, W2r, Wt2, HID);

    // ---- atomic-free two-level counting sorts ----
    part_hist_kernel<<<NBG + NBP, 256, 0, stream>>>(dst, edges, histG, histP, E, E2, NBUK, NBG);
    col_scan_kernel<<<2 * NBUK, 512, 0, stream>>>(histG, histP, scanTG, scanTP, totG, totP,
                                                  NBUK, NBG, NBP);
    bucket_scan_kernel<<<1, 512, 0, stream>>>(totG, totP, startG, startP, NBUK);
    part_scatter_kernel<<<NBG + NBP, 256, 0, stream>>>(src, dst, edges, scanTG, scanTP,
                                                       startG, startP, tmpG, tmpP,
                                                       E, E2, NBUK, NBG, NBP);
    bucket_sort_kernel<<<2 * NBUK, 256, 0, stream>>>(tmpG, tmpP,
                                                     startG, totG, startP, totP,
                                                     count, offs, nbr, pairs, N, Npad, NBUK);

    // ---- layer 1 ----
    agg1_kernel<<<(N + 3) / 4, 256, 0, stream>>>(xb, nbr, offs, count, agg1b, N);
    sage_gemm_mfma<2 * IN_CH, true><<<(N + 63) / 64, 256, 0, stream>>>(
        agg1b, xb, Wt1, b1, h, N);

    // ---- layer 2 ----
    agg2_kernel<<<(N + 3) / 4, 256, 0, stream>>>(h, nbr, offs, count, agg2b, N);
    sage_gemm_mfma<2 * HID, false><<<(N + 63) / 64, 256, 0, stream>>>(
        agg2b, h, Wt2, b2, z, N);

    // ---- decode ----
    decode2_kernel<<<(N + 3) / 4, 256, 0, stream>>>(z, pairs, offs + Npad, count + Npad, out, N);
}

// Round 10
// 744.236 us; speedup vs baseline: 2.0234x; 1.1008x over previous
//
#include <hip/hip_runtime.h>

#define IN_CH 128
#define HID   256
#define PB_VT 16            // 4096 edges per partition block

typedef __attribute__((ext_vector_type(8))) short bf16x8;
typedef __attribute__((ext_vector_type(4))) float f32x4;
typedef __attribute__((ext_vector_type(8))) unsigned short ushort8;

__device__ __forceinline__ ushort f2b(float f) {
    unsigned u = __float_as_uint(f);
    unsigned r = (u + 0x7fffu + ((u >> 16) & 1u)) >> 16;
    return (ushort)r;
}
__device__ __forceinline__ float b2f(ushort h) {
    return __uint_as_float(((unsigned)h) << 16);
}

// ================= atomic-free two-level counting sort =================
__global__ __launch_bounds__(256)
void part_hist_kernel(const int* __restrict__ dst, const int* __restrict__ edges,
                      int* __restrict__ histG, int* __restrict__ histP,
                      int E, int E2, int NBUK, int NBG) {
    __shared__ int hist[512];
    int t = threadIdx.x;
    bool isG = (int)blockIdx.x < NBG;
    int blk = isG ? blockIdx.x : blockIdx.x - NBG;
    for (int i = t; i < NBUK; i += 256) hist[i] = 0;
    __syncthreads();
    long long e0 = (long long)blk * (256 * PB_VT);
    if (isG) {
#pragma unroll
        for (int i = 0; i < PB_VT; i++) {
            long long e = e0 + i * 256 + t;
            if (e < E) atomicAdd(&hist[dst[e] >> 8], 1);
        }
    } else {
#pragma unroll
        for (int i = 0; i < PB_VT; i++) {
            long long e = e0 + i * 256 + t;
            if (e < E2) atomicAdd(&hist[edges[e * 2] >> 8], 1);
        }
    }
    __syncthreads();
    int* outp = isG ? histG : histP;
    for (int i = t; i < NBUK; i += 256) outp[(size_t)blk * NBUK + i] = hist[i];
}

__global__ __launch_bounds__(512)
void col_scan_kernel(const int* __restrict__ histG, const int* __restrict__ histP,
                     int* __restrict__ scanTG, int* __restrict__ scanTP,
                     int* __restrict__ totG, int* __restrict__ totP,
                     int NBUK, int NBG, int NBP) {
    __shared__ int s[512];
    int t = threadIdx.x;
    bool isG = (int)blockIdx.x < NBUK;
    int col = isG ? blockIdx.x : blockIdx.x - NBUK;
    const int* hist = isG ? histG : histP;
    int NBX = isG ? NBG : NBP;
    int v = (t < NBX) ? hist[(size_t)t * NBUK + col] : 0;
    s[t] = v;
    __syncthreads();
    for (int d = 1; d < 512; d <<= 1) {
        int u = (t >= d) ? s[t - d] : 0;
        __syncthreads(); s[t] += u; __syncthreads();
    }
    int* scanT = isG ? scanTG : scanTP;
    if (t < NBX) scanT[(size_t)col * NBX + t] = s[t] - v;
    if (t == 511) (isG ? totG : totP)[col] = s[511];
}

__global__ __launch_bounds__(512)
void bucket_scan_kernel(const int* __restrict__ totG, const int* __restrict__ totP,
                        int* __restrict__ startG, int* __restrict__ startP, int NBUK) {
    __shared__ int s[512];
    int t = threadIdx.x;
    int v = (t < NBUK) ? totG[t] : 0;
    s[t] = v; __syncthreads();
    for (int d = 1; d < 512; d <<= 1) { int u = (t >= d) ? s[t - d] : 0; __syncthreads(); s[t] += u; __syncthreads(); }
    if (t < NBUK) startG[t] = s[t] - v;
    __syncthreads();
    v = (t < NBUK) ? totP[t] : 0;
    s[t] = v; __syncthreads();
    for (int d = 1; d < 512; d <<= 1) { int u = (t >= d) ? s[t - d] : 0; __syncthreads(); s[t] += u; __syncthreads(); }
    if (t < NBUK) startP[t] = s[t] - v;
}

// Phase C: scatter into bucket-contiguous tmp (packed payloads).
__global__ __launch_bounds__(256)
void part_scatter_kernel(const int* __restrict__ src, const int* __restrict__ dst,
                         const int* __restrict__ edges,
                         const int* __restrict__ scanTG, const int* __restrict__ scanTP,
                         const int* __restrict__ startG, const int* __restrict__ startP,
                         unsigned* __restrict__ tmpG, unsigned long long* __restrict__ tmpP,
                         int E, int E2, int NBUK, int NBG, int NBP) {
    __shared__ int cur[512];
    int t = threadIdx.x;
    bool isG = (int)blockIdx.x < NBG;
    int blk = isG ? blockIdx.x : blockIdx.x - NBG;
    int NBX = isG ? NBG : NBP;
    const int* scanT = isG ? scanTG : scanTP;
    const int* bstart = isG ? startG : startP;
    for (int i = t; i < NBUK; i += 256)
        cur[i] = bstart[i] + scanT[(size_t)i * NBX + blk];
    __syncthreads();
    long long e0 = (long long)blk * (256 * PB_VT);
    if (isG) {
#pragma unroll
        for (int i = 0; i < PB_VT; i++) {
            long long e = e0 + i * 256 + t;
            if (e < E) {
                int d = dst[e];
                int pos = atomicAdd(&cur[d >> 8], 1);   // LDS atomic
                tmpG[pos] = ((unsigned)src[e] << 8) | (unsigned)(d & 255);
            }
        }
    } else {
#pragma unroll
        for (int i = 0; i < PB_VT; i++) {
            long long e = e0 + i * 256 + t;
            if (e < E2) {
                int2 ab = *(const int2*)(edges + e * 2);
                int pos = atomicAdd(&cur[ab.x >> 8], 1);
                tmpP[pos] = ((unsigned long long)(unsigned)(ab.x & 255) << 56)
                          | ((unsigned long long)(unsigned)ab.y << 32)
                          | (unsigned)e;
            }
        }
    }
}

__global__ __launch_bounds__(256)
void bucket_sort_kernel(const unsigned* __restrict__ tmpG, const unsigned long long* __restrict__ tmpP,
                        const int* __restrict__ startG, const int* __restrict__ totG,
                        const int* __restrict__ startP, const int* __restrict__ totP,
                        int* __restrict__ count, int* __restrict__ offs,
                        int* __restrict__ nbr, unsigned long long* __restrict__ pairs,
                        int N, int Npad, int NBUK) {
    __shared__ int h[256], loffs[256], lcur[256];
    int t = threadIdx.x;
    bool isG = (int)blockIdx.x < NBUK;
    int b = isG ? blockIdx.x : blockIdx.x - NBUK;
    int s = isG ? startG[b] : startP[b];
    int c = isG ? totG[b]   : totP[b];
    h[t] = 0;
    __syncthreads();
    if (isG) {
        for (int i = t; i < c; i += 256) atomicAdd(&h[tmpG[s + i] & 255], 1);
    } else {
        for (int i = t; i < c; i += 256) atomicAdd(&h[(int)(tmpP[s + i] >> 56)], 1);
    }
    __syncthreads();
    int v = h[t];
    loffs[t] = v;
    __syncthreads();
    for (int d = 1; d < 256; d <<= 1) {
        int u = (t >= d) ? loffs[t - d] : 0;
        __syncthreads(); loffs[t] += u; __syncthreads();
    }
    int excl = loffs[t] - v;
    lcur[t] = excl;
    int node = b * 256 + t;
    if (node < N) {
        int base = isG ? 0 : Npad;
        count[base + node] = v;
        offs[base + node] = s + excl;
    }
    __syncthreads();
    if (isG) {
        for (int i = t; i < c; i += 256) {
            unsigned w = tmpG[s + i];
            int p = atomicAdd(&lcur[w & 255], 1);
            nbr[s + p] = (int)(w >> 8);
        }
    } else {
        for (int i = t; i < c; i += 256) {
            unsigned long long w = tmpP[s + i];
            int p = atomicAdd(&lcur[(int)(w >> 56)], 1);
            pairs[s + p] = w & 0x00FFFFFFFFFFFFFFull;
        }
    }
}

// ================= bf16 conversions =================
__global__ void cvt_kernel(const float* __restrict__ in, ushort* __restrict__ o, int n4) {
    int i = blockIdx.x * 256 + threadIdx.x;
    if (i < n4) {
        float4 v = ((const float4*)in)[i];
        ushort4 u;
        u.x = f2b(v.x); u.y = f2b(v.y); u.z = f2b(v.z); u.w = f2b(v.w);
        ((ushort4*)o)[i] = u;
    }
}

template<bool PERM_K>
__global__ void prep_w_kernel(const float* __restrict__ Wl, const float* __restrict__ Wr,
                              ushort* __restrict__ Wt, int KH) {
    int ktot = 2 * KH;
    int idx = blockIdx.x * 256 + threadIdx.x;
    if (idx >= 256 * ktot) return;
    int n = idx / ktot, k = idx % ktot;
    int kh = (k < KH) ? k : (k - KH);
    int c = kh;
    if (PERM_K) {
        int j = kh & 63;
        c = (kh & ~63) | ((j & 3) * 16 + (j >> 2));
    }
    float v = (k < KH) ? Wl[(size_t)c * 256 + n] : Wr[(size_t)c * 256 + n];
    Wt[idx] = f2b(v);
}

// ================= gather-mean aggregation =================
__global__ void agg1_kernel(const ushort* __restrict__ xb, const int* __restrict__ nbr,
                            const int* __restrict__ offs, const int* __restrict__ count,
                            ushort* __restrict__ agg, int N) {
    int w = blockIdx.x * 4 + (threadIdx.x >> 6);
    if (w >= N) return;
    int lane = threadIdx.x & 63;
    int grp = lane >> 4, gl = lane & 15;
    int start = offs[w], cnt = count[w];
    float a0[8], a1[8];
#pragma unroll
    for (int i = 0; i < 8; i++) { a0[i] = 0.0f; a1[i] = 0.0f; }
    int j = grp;
    for (; j + 4 < cnt; j += 8) {
        int s0 = nbr[start + j];
        int s1 = nbr[start + j + 4];
        ushort8 v0 = *(const ushort8*)(xb + (size_t)s0 * IN_CH + gl * 8);
        ushort8 v1 = *(const ushort8*)(xb + (size_t)s1 * IN_CH + gl * 8);
#pragma unroll
        for (int i = 0; i < 8; i++) { a0[i] += b2f(v0[i]); a1[i] += b2f(v1[i]); }
    }
    if (j < cnt) {
        int s0 = nbr[start + j];
        ushort8 v0 = *(const ushort8*)(xb + (size_t)s0 * IN_CH + gl * 8);
#pragma unroll
        for (int i = 0; i < 8; i++) a0[i] += b2f(v0[i]);
    }
#pragma unroll
    for (int i = 0; i < 8; i++) {
        a0[i] += a1[i];
        a0[i] += __shfl_xor(a0[i], 16, 64);
        a0[i] += __shfl_xor(a0[i], 32, 64);
    }
    if (grp == 0) {
        float r = 1.0f / fmaxf((float)cnt, 1.0f);
        ushort8 o;
#pragma unroll
        for (int i = 0; i < 8; i++) o[i] = f2b(a0[i] * r);
        *(ushort8*)(agg + (size_t)w * IN_CH + gl * 8) = o;
    }
}

__global__ void agg2_kernel(const ushort* __restrict__ h, const int* __restrict__ nbr,
                            const int* __restrict__ offs, const int* __restrict__ count,
                            ushort* __restrict__ agg, int N) {
    int w = blockIdx.x * 4 + (threadIdx.x >> 6);
    if (w >= N) return;
    int lane = threadIdx.x & 63;
    int half = lane >> 5, hl = lane & 31;
    int start = offs[w], cnt = count[w];
    float a0[8], a1[8];
#pragma unroll
    for (int i = 0; i < 8; i++) { a0[i] = 0.0f; a1[i] = 0.0f; }
    int j = half;
    for (; j + 6 < cnt; j += 8) {
        int s0 = nbr[start + j];
        int s1 = nbr[start + j + 2];
        int s2 = nbr[start + j + 4];
        int s3 = nbr[start + j + 6];
        ushort8 v0 = *(const ushort8*)(h + (size_t)s0 * HID + hl * 8);
        ushort8 v1 = *(const ushort8*)(h + (size_t)s1 * HID + hl * 8);
        ushort8 v2 = *(const ushort8*)(h + (size_t)s2 * HID + hl * 8);
        ushort8 v3 = *(const ushort8*)(h + (size_t)s3 * HID + hl * 8);
#pragma unroll
        for (int i = 0; i < 8; i++) {
            a0[i] += b2f(v0[i]) + b2f(v2[i]);
            a1[i] += b2f(v1[i]) + b2f(v3[i]);
        }
    }
    for (; j < cnt; j += 2) {
        int s0 = nbr[start + j];
        ushort8 v0 = *(const ushort8*)(h + (size_t)s0 * HID + hl * 8);
#pragma unroll
        for (int i = 0; i < 8; i++) a0[i] += b2f(v0[i]);
    }
#pragma unroll
    for (int i = 0; i < 8; i++) {
        a0[i] += a1[i];
        a0[i] += __shfl_xor(a0[i], 32, 64);
    }
    if (half == 0) {
        float r = 1.0f / fmaxf((float)cnt, 1.0f);
        ushort8 o;
#pragma unroll
        for (int i = 0; i < 8; i++) o[i] = f2b(a0[i] * r);
        *(ushort8*)(agg + (size_t)w * HID + hl * 8) = o;
    }
}

// ================= MFMA GEMM: 512 threads, 32 AGPR acc, 2x occupancy =================
// 8 waves/block; wave w owns all 64 rows x cols [w*32, w*32+32).
// acc = 4 row-tiles x 2 col-tiles = 32 f32/lane (halved vs 4x4 layout).
template<int KTOT, bool RELU>
__global__ __launch_bounds__(512, 4)
void sage_gemm_mfma(const ushort* __restrict__ Aleft, const ushort* __restrict__ Aright,
                    const ushort* __restrict__ Wt, const float* __restrict__ bias,
                    ushort* __restrict__ out, int N) {
    constexpr int KH = KTOT / 2;
    __shared__ ushort smem[2048 + 8192];       // As[2048] | Bs[8192]
    ushort* As = smem;
    ushort* Bs = smem + 2048;

    const int t = threadIdx.x;                 // 0..511
    const int wave = t >> 6;                   // 0..7
    const int lane = t & 63;
    const int quad = lane >> 4;
    const int l16  = lane & 15;
    const int rowBase = blockIdx.x * 64;

    // A staging: row = t>>3, 4-short (8B) chunk at aK = (t&7)*4
    const int aRow = t >> 3;
    const int aK   = (t & 7) * 4;
    const bool aRowOK = (rowBase + aRow) < N;
    // fragment-order LDS address for (aRow, aK)
    const int aLds = ((aRow >> 4) * 64 + (aRow & 15) * 4 + (aK >> 3)) * 8 + (aK & 7);

    // B staging: n = t>>1, two 16B chunks ch = (t&1)*2 + {0,1}
    const int bN   = t >> 1;
    const int bCh0 = (t & 1) * 2;
    const int bFragBase = (bN >> 6) * 256 + ((bN >> 4) & 3) * 64 + (bN & 15) * 4;

    // fragment read addresses
    int bFrag[2];
#pragma unroll
    for (int nt = 0; nt < 2; nt++) {
        int c = wave * 32 + nt * 16 + l16;
        bFrag[nt] = ((c >> 6) * 256 + ((c >> 4) & 3) * 64 + (c & 15) * 4 + quad) * 8;
    }

    f32x4 acc[4][2];
#pragma unroll
    for (int i = 0; i < 4; i++)
#pragma unroll
        for (int j = 0; j < 2; j++) acc[i][j] = (f32x4)0.0f;

    // prefetch k0 = 0
    unsigned long long aReg = 0ull;
    ulonglong2 bReg[2];
    if (aRowOK)
        aReg = *(const unsigned long long*)(Aleft + (size_t)(rowBase + aRow) * KH + aK);
    bReg[0] = *(const ulonglong2*)(Wt + (size_t)bN * KTOT + bCh0 * 8);
    bReg[1] = *(const ulonglong2*)(Wt + (size_t)bN * KTOT + (bCh0 + 1) * 8);

    for (int k0 = 0; k0 < KTOT; k0 += 32) {
        __syncthreads();                       // prior ds_reads done
        *(unsigned long long*)&As[aLds] = aReg;
        *(ulonglong2*)&Bs[(bFragBase + bCh0) * 8]     = bReg[0];
        *(ulonglong2*)&Bs[(bFragBase + bCh0 + 1) * 8] = bReg[1];

        int kn = k0 + 32;
        if (kn < KTOT) {                       // next prefetch overlaps MFMA below
            if (aRowOK) {
                const ushort* Ap = (kn < KH)
                    ? (Aleft  + (size_t)(rowBase + aRow) * KH + (kn + aK))
                    : (Aright + (size_t)(rowBase + aRow) * KH + (kn - KH + aK));
                aReg = *(const unsigned long long*)Ap;
            }
            bReg[0] = *(const ulonglong2*)(Wt + (size_t)bN * KTOT + kn + bCh0 * 8);
            bReg[1] = *(const ulonglong2*)(Wt + (size_t)bN * KTOT + kn + (bCh0 + 1) * 8);
        }
        __syncthreads();

        bf16x8 af[4], bf[2];
#pragma unroll
        for (int mt = 0; mt < 4; mt++)
            af[mt] = *(const bf16x8*)&As[(mt * 64 + l16 * 4 + quad) * 8];
#pragma unroll
        for (int nt = 0; nt < 2; nt++)
            bf[nt] = *(const bf16x8*)&Bs[bFrag[nt]];
#pragma unroll
        for (int mt = 0; mt < 4; mt++)
#pragma unroll
            for (int nt = 0; nt < 2; nt++)
                acc[mt][nt] = __builtin_amdgcn_mfma_f32_16x16x32_bf16(
                    af[mt], bf[nt], acc[mt][nt], 0, 0, 0);
    }

    float bv[2];
#pragma unroll
    for (int nt = 0; nt < 2; nt++) bv[nt] = bias[wave * 32 + nt * 16 + l16]; // logical col
    ushort* tile = smem;                       // 32 x 256 shorts = 16 KB

#pragma unroll
    for (int hf = 0; hf < 2; hf++) {
        __syncthreads();
#pragma unroll
        for (int mh = 0; mh < 2; mh++) {
            int mt = hf * 2 + mh;
#pragma unroll
            for (int reg = 0; reg < 4; reg++) {
                int rl = mh * 16 + quad * 4 + reg;
                float v0 = acc[mt][0][reg] + bv[0];
                float v1 = acc[mt][1][reg] + bv[1];
                if (RELU) { v0 = fmaxf(v0, 0.0f); v1 = fmaxf(v1, 0.0f); }
                ushort2 o;
                o.x = f2b(v0); o.y = f2b(v1);
                // P-permuted position: (c&~63) | (l16*4 + ((c>>4)&3))
                *(ushort2*)&tile[rl * 256 + (wave >> 1) * 64 + l16 * 4 + (wave & 1) * 2] = o;
            }
        }
        __syncthreads();
#pragma unroll
        for (int i = 0; i < 2; i++) {
            int ch = i * 512 + t;              // 1024 chunks of 16B
            int rl = ch >> 5, c16 = ch & 31;
            int row = rowBase + hf * 32 + rl;
            if (row < N)
                *(ushort8*)(out + (size_t)row * 256 + c16 * 8) =
                    *(const ushort8*)&tile[rl * 256 + c16 * 8];
        }
    }
}

// ================= decode: one wave per a-node, 4-deep per half =================
__global__ void decode2_kernel(const ushort* __restrict__ z,
                               const unsigned long long* __restrict__ pairs,
                               const int* __restrict__ offsA, const int* __restrict__ countA,
                               float* __restrict__ out, int N) {
    int a = blockIdx.x * 4 + (threadIdx.x >> 6);
    if (a >= N) return;
    int cnt = countA[a];
    if (cnt == 0) return;
    int lane = threadIdx.x & 63;
    int half = lane >> 5, hl = lane & 31;
    int start = offsA[a];

    float ar[8];
    {
        ushort8 va = *(const ushort8*)(z + (size_t)a * HID + hl * 8);
#pragma unroll
        for (int i = 0; i < 8; i++) ar[i] = b2f(va[i]);
    }

    int j = half;
    for (; j + 6 < cnt; j += 8) {
        unsigned long long p0 = pairs[start + j];
        unsigned long long p1 = pairs[start + j + 2];
        unsigned long long p2 = pairs[start + j + 4];
        unsigned long long p3 = pairs[start + j + 6];
        int b0 = (int)(p0 >> 32), e0 = (int)(p0 & 0xffffffffu);
        int b1 = (int)(p1 >> 32), e1 = (int)(p1 & 0xffffffffu);
        int b2 = (int)(p2 >> 32), e2 = (int)(p2 & 0xffffffffu);
        int b3 = (int)(p3 >> 32), e3 = (int)(p3 & 0xffffffffu);
        ushort8 v0 = *(const ushort8*)(z + (size_t)b0 * HID + hl * 8);
        ushort8 v1 = *(const ushort8*)(z + (size_t)b1 * HID + hl * 8);
        ushort8 v2 = *(const ushort8*)(z + (size_t)b2 * HID + hl * 8);
        ushort8 v3 = *(const ushort8*)(z + (size_t)b3 * HID + hl * 8);
        float s0 = 0.f, s1 = 0.f, s2 = 0.f, s3 = 0.f;
#pragma unroll
        for (int i = 0; i < 8; i++) {
            s0 = fmaf(ar[i], b2f(v0[i]), s0);
            s1 = fmaf(ar[i], b2f(v1[i]), s1);
            s2 = fmaf(ar[i], b2f(v2[i]), s2);
            s3 = fmaf(ar[i], b2f(v3[i]), s3);
        }
#pragma unroll
        for (int off = 1; off < 32; off <<= 1) {
            s0 += __shfl_xor(s0, off, 64);
            s1 += __shfl_xor(s1, off, 64);
            s2 += __shfl_xor(s2, off, 64);
            s3 += __shfl_xor(s3, off, 64);
        }
        if (hl == 0) { out[e0] = s0; out[e1] = s1; out[e2] = s2; out[e3] = s3; }
    }
    for (; j < cnt; j += 2) {
        unsigned long long p0 = pairs[start + j];
        int b0 = (int)(p0 >> 32), e0 = (int)(p0 & 0xffffffffu);
        ushort8 v0 = *(const ushort8*)(z + (size_t)b0 * HID + hl * 8);
        float s0 = 0.f;
#pragma unroll
        for (int i = 0; i < 8; i++) s0 = fmaf(ar[i], b2f(v0[i]), s0);
#pragma unroll
        for (int off = 1; off < 32; off <<= 1) s0 += __shfl_xor(s0, off, 64);
        if (hl == 0) out[e0] = s0;
    }
}

extern "C" void kernel_launch(void* const* d_in, const int* in_sizes, int n_in,
                              void* d_out, int out_size, void* d_ws, size_t ws_size,
                              hipStream_t stream) {
    const float* x    = (const float*)d_in[0];
    const int* eidx   = (const int*)d_in[1];
    const int* edges  = (const int*)d_in[2];
    const float* W1l  = (const float*)d_in[3];
    const float* b1   = (const float*)d_in[4];
    const float* W1r  = (const float*)d_in[5];
    const float* W2l  = (const float*)d_in[6];
    const float* b2   = (const float*)d_in[7];
    const float* W2r  = (const float*)d_in[8];
    float* out = (float*)d_out;

    const int N  = in_sizes[0] / IN_CH;
    const int E  = in_sizes[1] / 2;
    const int E2 = in_sizes[2] / 2;
    const int* src = eidx;
    const int* dst = eidx + E;

    const int NBUK = (N + 255) >> 8;            // 256-node buckets (<=512)
    const int Npad = NBUK << 8;
    const int NBG  = (E  + 256 * PB_VT - 1) / (256 * PB_VT);   // <=512
    const int NBP  = (E2 + 256 * PB_VT - 1) / (256 * PB_VT);

    int* count   = (int*)d_ws;
    int* offs    = count + 2 * Npad;
    int* histG   = offs + 2 * Npad;
    int* histP   = histG + (size_t)NBG * NBUK;
    int* scanTG  = histP + (size_t)NBP * NBUK;
    int* scanTP  = scanTG + (size_t)NBUK * NBG;
    int* totG    = scanTP + (size_t)NBUK * NBP;
    int* totP    = totG + 512;
    int* startG  = totP + 512;
    int* startP  = startG + 512;
    int* nbr     = startP + 512;
    size_t intWords = (size_t)(nbr - (int*)d_ws) + E;
    intWords = (intWords + 1) & ~(size_t)1;
    unsigned long long* pairs = (unsigned long long*)((int*)d_ws + intWords);
    ushort* xb    = (ushort*)(pairs + E2);
    ushort* agg1b = xb + (size_t)N * IN_CH;
    ushort* agg2b = xb;                         // overlay after gemm1
    ushort* h     = agg1b + (size_t)N * IN_CH;
    ushort* z     = h + (size_t)N * HID;
    ushort* Wt1   = z + (size_t)N * HID;
    ushort* Wt2   = Wt1 + 256 * 256;
    // packed tmp partition arrays overlay z (dead until gemm2)
    unsigned* tmpG = (unsigned*)z;
    unsigned long long* tmpP = (unsigned long long*)(tmpG + ((E + 1) & ~1));

    // ---- conversions ----
    cvt_kernel<<<((N * IN_CH / 4) + 255) / 256, 256, 0, stream>>>(x, xb, N * IN_CH / 4);
    prep_w_kernel<false><<<(256 * 256 + 255) / 256, 256, 0, stream>>>(W1l, W1r, Wt1, IN_CH);
    prep_w_kernel<true><<<(256 * 512 + 255) / 256, 256, 0, stream>>>(W2l, W2r, Wt2, HID);

    // ---- atomic-free two-level counting sorts ----
    part_hist_kernel<<<NBG + NBP, 256, 0, stream>>>(dst, edges, histG, histP, E, E2, NBUK, NBG);
    col_scan_kernel<<<2 * NBUK, 512, 0, stream>>>(histG, histP, scanTG, scanTP, totG, totP,
                                                  NBUK, NBG, NBP);
    bucket_scan_kernel<<<1, 512, 0, stream>>>(totG, totP, startG, startP, NBUK);
    part_scatter_kernel<<<NBG + NBP, 256, 0, stream>>>(src, dst, edges, scanTG, scanTP,
                                                       startG, startP, tmpG, tmpP,
                                                       E, E2, NBUK, NBG, NBP);
    bucket_sort_kernel<<<2 * NBUK, 256, 0, stream>>>(tmpG, tmpP,
                                                     startG, totG, startP, totP,
                                                     count, offs, nbr, pairs, N, Npad, NBUK);

    // ---- layer 1 ----
    agg1_kernel<<<(N + 3) / 4, 256, 0, stream>>>(xb, nbr, offs, count, agg1b, N);
    sage_gemm_mfma<2 * IN_CH, true><<<(N + 63) / 64, 512, 0, stream>>>(
        agg1b, xb, Wt1, b1, h, N);

    // ---- layer 2 ----
    agg2_kernel<<<(N + 3) / 4, 256, 0, stream>>>(h, nbr, offs, count, agg2b, N);
    sage_gemm_mfma<2 * HID, false><<<(N + 63) / 64, 512, 0, stream>>>(
        agg2b, h, Wt2, b2, z, N);

    // ---- decode ----
    decode2_kernel<<<(N + 3) / 4, 256, 0, stream>>>(z, pairs, offs + Npad, count + Npad, out, N);
}